// Round 1
// baseline (400.762 us; speedup 1.0000x reference)
//
#include <hip/hip_runtime.h>
#include <cmath>

#define Bb 8192
#define Dd 2048
#define Rr 64
#define Ee 4
#define Ll 3

typedef __bf16 bf16x8 __attribute__((ext_vector_type(8)));
typedef float f32x4 __attribute__((ext_vector_type(4)));
typedef unsigned short u16x8 __attribute__((ext_vector_type(8)));
typedef unsigned short u16x4 __attribute__((ext_vector_type(4)));

__device__ __forceinline__ unsigned short f2bf(float f){
  unsigned u = __builtin_bit_cast(unsigned, f);
  u += 0x7fffu + ((u >> 16) & 1u);
  return (unsigned short)(u >> 16);
}
__device__ __forceinline__ float bf2f(unsigned short h){
  return __builtin_bit_cast(float, ((unsigned)h) << 16);
}

// ---------------- prep: cast inputs (B,D) f32 -> bf16 ----------------
__global__ __launch_bounds__(256) void cast_x_k(const float* __restrict__ x,
                                                unsigned short* __restrict__ xb){
  const int n4 = Bb * Dd / 4;
  for (int i = blockIdx.x * blockDim.x + threadIdx.x; i < n4; i += gridDim.x * blockDim.x){
    f32x4 v = *((const f32x4*)x + i);
    u16x4 o;
    o[0] = f2bf(v[0]); o[1] = f2bf(v[1]); o[2] = f2bf(v[2]); o[3] = f2bf(v[3]);
    *((u16x4*)xb + i) = o;
  }
}

// ---------------- prep: transpose/cast weights ----------------
// VfT[l][n][d] = V[l, e=n/64, d, r=n%64]          (256 x 2048 per layer, N-major)
// UfT[l][d][k] = U[l, e=k/64, d, s=k%64]          (2048 x 256 per layer, N-major)
// CbT[l][n][k] = (n/64==k/64) ? C[l, e, s=n%64, r=k%64] : 0   (256 x 256, N-major)
// gw16[e][d]   = bf16(gate_w[e][d])
__global__ __launch_bounds__(256) void prep_w_k(const float* __restrict__ U,
                                                const float* __restrict__ V,
                                                const float* __restrict__ C,
                                                const float* __restrict__ gw,
                                                unsigned short* __restrict__ VfT,
                                                unsigned short* __restrict__ UfT,
                                                unsigned short* __restrict__ CbT,
                                                unsigned short* __restrict__ gw16){
  const int NV = Ll * 256 * Dd;
  const int NU = Ll * Dd * 256;
  const int NC = Ll * 256 * 256;
  const int NG = Ee * Dd;
  const int total = NV + NU + NC + NG;
  for (int idx = blockIdx.x * blockDim.x + threadIdx.x; idx < total; idx += gridDim.x * blockDim.x){
    if (idx < NV){
      int l = idx / (256 * Dd); int rem = idx - l * 256 * Dd;
      int n = rem / Dd, d = rem - n * Dd;
      int e = n >> 6, r = n & 63;
      VfT[idx] = f2bf(V[(((size_t)l * Ee + e) * Dd + d) * Rr + r]);
    } else if (idx < NV + NU){
      int j = idx - NV;
      int l = j / (Dd * 256); int rem = j - l * Dd * 256;
      int d = rem / 256, k = rem - d * 256;
      int e = k >> 6, s = k & 63;
      UfT[j] = f2bf(U[(((size_t)l * Ee + e) * Dd + d) * Rr + s]);
    } else if (idx < NV + NU + NC){
      int j = idx - NV - NU;
      int l = j / (256 * 256); int rem = j - l * 256 * 256;
      int n = rem / 256, k = rem - n * 256;
      int e = n >> 6, s = n & 63, e2 = k >> 6, r = k & 63;
      float v = (e == e2) ? C[(((size_t)l * Ee + e) * Rr + s) * Rr + r] : 0.f;
      CbT[j] = f2bf(v);
    } else {
      int j = idx - NV - NU - NC;
      gw16[j] = f2bf(gw[j]);
    }
  }
}

// ---------------- gate: logits = x @ gate_w^T, softmax -> gs (B,4) ----------------
// block = 256 threads, 16 rows per block; 16 threads per row each own a 128-wide d-chunk
__global__ __launch_bounds__(256) void gate_k(const unsigned short* __restrict__ xb,
                                              const unsigned short* __restrict__ gw16,
                                              float* __restrict__ gs){
  int tid = threadIdx.x;
  int row = blockIdx.x * 16 + (tid >> 4);
  int ch  = tid & 15;
  const unsigned short* xr = xb + (size_t)row * Dd + ch * 128;
  const unsigned short* g0 = gw16 + ch * 128;
  float s0 = 0.f, s1 = 0.f, s2 = 0.f, s3 = 0.f;
  for (int j = 0; j < 16; j++){
    u16x8 xv = *(const u16x8*)(xr + j * 8);
    u16x8 g0v = *(const u16x8*)(g0 + 0 * Dd + j * 8);
    u16x8 g1v = *(const u16x8*)(g0 + 1 * Dd + j * 8);
    u16x8 g2v = *(const u16x8*)(g0 + 2 * Dd + j * 8);
    u16x8 g3v = *(const u16x8*)(g0 + 3 * Dd + j * 8);
    #pragma unroll
    for (int u = 0; u < 8; u++){
      float xf = bf2f(xv[u]);
      s0 += xf * bf2f(g0v[u]);
      s1 += xf * bf2f(g1v[u]);
      s2 += xf * bf2f(g2v[u]);
      s3 += xf * bf2f(g3v[u]);
    }
  }
  #pragma unroll
  for (int m = 1; m < 16; m <<= 1){
    s0 += __shfl_xor(s0, m, 64);
    s1 += __shfl_xor(s1, m, 64);
    s2 += __shfl_xor(s2, m, 64);
    s3 += __shfl_xor(s3, m, 64);
  }
  if (ch == 0){
    float mx = fmaxf(fmaxf(s0, s1), fmaxf(s2, s3));
    float e0 = __expf(s0 - mx), e1 = __expf(s1 - mx), e2 = __expf(s2 - mx), e3 = __expf(s3 - mx);
    float inv = 1.f / (e0 + e1 + e2 + e3);
    f32x4 g; g[0] = e0 * inv; g[1] = e1 * inv; g[2] = e2 * inv; g[3] = e3 * inv;
    *(f32x4*)(gs + (size_t)row * 4) = g;
  }
}

// ---------------- generic MFMA GEMM: (M x K)bf16 @ (K x N)bf16 -> epilogue ----------------
// A: row-major M x K. BT: N-major (i.e. row n holds column n of B): N x K.
// Tile 64(M) x 128(N), BK=32. 4 waves as 2x2, each wave 32x64 (2x4 frags of 16x16).
// EPI 0: out_bf[row*ncols+col] = bf16(tanh(acc))                        (G1: vx)
// EPI 1: out_bf[row*ncols+col] = bf16(gs[row*4 + col/64] * tanh(acc))   (G2: W)
// EPI 2: xn = xold + x0*(biasrow[col] + acc); out_f = xn; opt out_bf = bf16(xn)  (G3)
template<int EPI>
__global__ __launch_bounds__(256) void gemm_k(const unsigned short* __restrict__ A,
                                              const unsigned short* __restrict__ BT,
                                              int K,
                                              unsigned short* __restrict__ out_bf,
                                              float* __restrict__ out_f,
                                              const float* __restrict__ gs,
                                              const float* __restrict__ x0,
                                              const float* __restrict__ xold,
                                              const float* __restrict__ biasrow,
                                              int ncols){
  const int bm0 = blockIdx.x * 64;
  const int bn0 = blockIdx.y * 128;
  const int tid = threadIdx.x;
  const int lane = tid & 63;
  const int wv = tid >> 6;
  const int wm = wv >> 1, wn = wv & 1;

  __shared__ unsigned short As[64][40];   // +8 pad vs bank conflicts
  __shared__ unsigned short Bs[128][40];

  f32x4 acc[2][4] = {};

  const int arow = tid >> 2;   // 0..63
  const int aseg = tid & 3;    // 0..3, 8 bf16 each

  for (int k0 = 0; k0 < K; k0 += 32){
    u16x8 areg  = *(const u16x8*)(A  + (size_t)(bm0 + arow) * K + k0 + aseg * 8);
    u16x8 breg0 = *(const u16x8*)(BT + (size_t)(bn0 + arow) * K + k0 + aseg * 8);
    u16x8 breg1 = *(const u16x8*)(BT + (size_t)(bn0 + arow + 64) * K + k0 + aseg * 8);
    __syncthreads();
    *(u16x8*)(&As[arow][aseg * 8]) = areg;
    *(u16x8*)(&Bs[arow][aseg * 8]) = breg0;
    *(u16x8*)(&Bs[arow + 64][aseg * 8]) = breg1;
    __syncthreads();

    bf16x8 af[2];
    #pragma unroll
    for (int mi = 0; mi < 2; mi++)
      af[mi] = *reinterpret_cast<const bf16x8*>(&As[wm * 32 + mi * 16 + (lane & 15)][(lane >> 4) * 8]);
    #pragma unroll
    for (int nj = 0; nj < 4; nj++){
      bf16x8 bfr = *reinterpret_cast<const bf16x8*>(&Bs[wn * 64 + nj * 16 + (lane & 15)][(lane >> 4) * 8]);
      #pragma unroll
      for (int mi = 0; mi < 2; mi++)
        acc[mi][nj] = __builtin_amdgcn_mfma_f32_16x16x32_bf16(af[mi], bfr, acc[mi][nj], 0, 0, 0);
    }
  }

  #pragma unroll
  for (int mi = 0; mi < 2; mi++){
    #pragma unroll
    for (int nj = 0; nj < 4; nj++){
      #pragma unroll
      for (int q = 0; q < 4; q++){
        int row = bm0 + wm * 32 + mi * 16 + (lane >> 4) * 4 + q;
        int col = bn0 + wn * 64 + nj * 16 + (lane & 15);
        float v = acc[mi][nj][q];
        if constexpr (EPI == 0){
          out_bf[(size_t)row * ncols + col] = f2bf(tanhf(v));
        } else if constexpr (EPI == 1){
          float g = gs[(size_t)row * 4 + (col >> 6)];
          out_bf[(size_t)row * ncols + col] = f2bf(g * tanhf(v));
        } else {
          size_t o = (size_t)row * ncols + col;
          float xn = xold[o] + x0[o] * (biasrow[col] + v);
          out_f[o] = xn;
          if (out_bf) out_bf[o] = f2bf(xn);
        }
      }
    }
  }
}

extern "C" void kernel_launch(void* const* d_in, const int* in_sizes, int n_in,
                              void* d_out, int out_size, void* d_ws, size_t ws_size,
                              hipStream_t stream){
  (void)in_sizes; (void)n_in; (void)out_size;
  const float* inp  = (const float*)d_in[0];
  const float* U    = (const float*)d_in[1];
  const float* V    = (const float*)d_in[2];
  const float* C    = (const float*)d_in[3];
  const float* gw   = (const float*)d_in[4];
  const float* bias = (const float*)d_in[5];
  float* out = (float*)d_out;

  char* ws = (char*)d_ws;
  size_t o = 0;
  unsigned short* xb  = (unsigned short*)(ws + o); o += (size_t)Bb * Dd * 2;       // 33.55 MB
  unsigned short* vxt = (unsigned short*)(ws + o); o += (size_t)Bb * 256 * 2;      //  4.19 MB
  unsigned short* wb  = (unsigned short*)(ws + o); o += (size_t)Bb * 256 * 2;      //  4.19 MB
  float*          gsb = (float*)(ws + o);          o += (size_t)Bb * 4 * 4;        //  0.13 MB
  unsigned short* vft = (unsigned short*)(ws + o); o += (size_t)Ll * 256 * Dd * 2; //  3.15 MB
  unsigned short* uft = (unsigned short*)(ws + o); o += (size_t)Ll * Dd * 256 * 2; //  3.15 MB
  unsigned short* cbt = (unsigned short*)(ws + o); o += (size_t)Ll * 256 * 256 * 2;//  0.39 MB
  unsigned short* g16 = (unsigned short*)(ws + o); o += (size_t)Ee * Dd * 2;       //  0.02 MB
  if (ws_size < o) return;  // workspace too small -> visible as zero-output failure

  cast_x_k<<<2048, 256, 0, stream>>>(inp, xb);
  prep_w_k<<<2048, 256, 0, stream>>>(U, V, C, gw, vft, uft, cbt, g16);

  for (int l = 0; l < Ll; l++){
    gate_k<<<Bb / 16, 256, 0, stream>>>(xb, g16, gsb);
    // G1: T = X @ Vf  -> vxt = bf16(tanh(T))          M=8192 K=2048 N=256
    gemm_k<0><<<dim3(Bb / 64, 256 / 128), 256, 0, stream>>>(
        xb, vft + (size_t)l * 256 * Dd, Dd, vxt, nullptr, nullptr, nullptr, nullptr, nullptr, 256);
    // G2: CX = vxt @ Cbd -> wb = bf16(gs * tanh(CX))  M=8192 K=256 N=256
    gemm_k<1><<<dim3(Bb / 64, 256 / 128), 256, 0, stream>>>(
        vxt, cbt + (size_t)l * 256 * 256, 256, wb, nullptr, gsb, nullptr, nullptr, nullptr, 256);
    // G3: Y = wb @ Uf -> x_new = x_old + x0*(bias + Y)  M=8192 K=256 N=2048
    const float* xold = (l == 0) ? inp : out;
    unsigned short* xbn = (l < Ll - 1) ? xb : nullptr;
    gemm_k<2><<<dim3(Bb / 64, Dd / 128), 256, 0, stream>>>(
        wb, uft + (size_t)l * Dd * 256, 256, xbn, out, nullptr, inp, xold, bias + (size_t)l * Dd, Dd);
  }
}

// Round 2
// 394.495 us; speedup vs baseline: 1.0159x; 1.0159x over previous
//
#include <hip/hip_runtime.h>
#include <cmath>

#define Bb 8192
#define Dd 2048
#define Rr 64
#define Ee 4
#define Ll 3

typedef __bf16 bf16x8 __attribute__((ext_vector_type(8)));
typedef float f32x4 __attribute__((ext_vector_type(4)));
typedef unsigned short u16x8 __attribute__((ext_vector_type(8)));
typedef unsigned short u16x4 __attribute__((ext_vector_type(4)));

__device__ __forceinline__ unsigned short f2bf(float f){
  unsigned u = __builtin_bit_cast(unsigned, f);
  u += 0x7fffu + ((u >> 16) & 1u);
  return (unsigned short)(u >> 16);
}
__device__ __forceinline__ float bf2f(unsigned short h){
  return __builtin_bit_cast(float, ((unsigned)h) << 16);
}

// ---------------- prep: cast inputs (B,D) f32 -> bf16 (xb, and optional x0 copy) ----
__global__ __launch_bounds__(256) void cast_x_k(const float* __restrict__ x,
                                                unsigned short* __restrict__ xb,
                                                unsigned short* __restrict__ xb0){
  const int n4 = Bb * Dd / 4;
  for (int i = blockIdx.x * blockDim.x + threadIdx.x; i < n4; i += gridDim.x * blockDim.x){
    f32x4 v = *((const f32x4*)x + i);
    u16x4 o;
    o[0] = f2bf(v[0]); o[1] = f2bf(v[1]); o[2] = f2bf(v[2]); o[3] = f2bf(v[3]);
    *((u16x4*)xb + i) = o;
    if (xb0) *((u16x4*)xb0 + i) = o;
  }
}

// ---------------- prep: transpose/cast weights ----------------
__global__ __launch_bounds__(256) void prep_w_k(const float* __restrict__ U,
                                                const float* __restrict__ V,
                                                const float* __restrict__ C,
                                                const float* __restrict__ gw,
                                                unsigned short* __restrict__ VfT,
                                                unsigned short* __restrict__ UfT,
                                                unsigned short* __restrict__ CbT,
                                                unsigned short* __restrict__ gw16){
  const int NV = Ll * 256 * Dd;
  const int NU = Ll * Dd * 256;
  const int NC = Ll * 256 * 256;
  const int NG = Ee * Dd;
  const int total = NV + NU + NC + NG;
  for (int idx = blockIdx.x * blockDim.x + threadIdx.x; idx < total; idx += gridDim.x * blockDim.x){
    if (idx < NV){
      int l = idx / (256 * Dd); int rem = idx - l * 256 * Dd;
      int n = rem / Dd, d = rem - n * Dd;
      int e = n >> 6, r = n & 63;
      VfT[idx] = f2bf(V[(((size_t)l * Ee + e) * Dd + d) * Rr + r]);
    } else if (idx < NV + NU){
      int j = idx - NV;
      int l = j / (Dd * 256); int rem = j - l * Dd * 256;
      int d = rem / 256, k = rem - d * 256;
      int e = k >> 6, s = k & 63;
      UfT[j] = f2bf(U[(((size_t)l * Ee + e) * Dd + d) * Rr + s]);
    } else if (idx < NV + NU + NC){
      int j = idx - NV - NU;
      int l = j / (256 * 256); int rem = j - l * 256 * 256;
      int n = rem / 256, k = rem - n * 256;
      int e = n >> 6, s = n & 63, e2 = k >> 6, r = k & 63;
      float v = (e == e2) ? C[(((size_t)l * Ee + e) * Rr + s) * Rr + r] : 0.f;
      CbT[j] = f2bf(v);
    } else {
      int j = idx - NV - NU - NC;
      gw16[j] = f2bf(gw[j]);
    }
  }
}

// ---------------- zero a fp32 buffer (for split-K atomics) ----------------
__global__ __launch_bounds__(256) void zero_k(float* __restrict__ p, int n4){
  for (int i = blockIdx.x * blockDim.x + threadIdx.x; i < n4; i += gridDim.x * blockDim.x)
    *((f32x4*)p + i) = f32x4{0.f, 0.f, 0.f, 0.f};
}

// ---------------- gate: logits = x @ gate_w^T, softmax -> gs (B,4) ----------------
__global__ __launch_bounds__(256) void gate_k(const unsigned short* __restrict__ xb,
                                              const unsigned short* __restrict__ gw16,
                                              float* __restrict__ gs){
  int tid = threadIdx.x;
  int row = blockIdx.x * 16 + (tid >> 4);
  int ch  = tid & 15;
  const unsigned short* xr = xb + (size_t)row * Dd + ch * 128;
  const unsigned short* g0 = gw16 + ch * 128;
  float s0 = 0.f, s1 = 0.f, s2 = 0.f, s3 = 0.f;
  for (int j = 0; j < 16; j++){
    u16x8 xv = *(const u16x8*)(xr + j * 8);
    u16x8 g0v = *(const u16x8*)(g0 + 0 * Dd + j * 8);
    u16x8 g1v = *(const u16x8*)(g0 + 1 * Dd + j * 8);
    u16x8 g2v = *(const u16x8*)(g0 + 2 * Dd + j * 8);
    u16x8 g3v = *(const u16x8*)(g0 + 3 * Dd + j * 8);
    #pragma unroll
    for (int u = 0; u < 8; u++){
      float xf = bf2f(xv[u]);
      s0 += xf * bf2f(g0v[u]);
      s1 += xf * bf2f(g1v[u]);
      s2 += xf * bf2f(g2v[u]);
      s3 += xf * bf2f(g3v[u]);
    }
  }
  #pragma unroll
  for (int m = 1; m < 16; m <<= 1){
    s0 += __shfl_xor(s0, m, 64);
    s1 += __shfl_xor(s1, m, 64);
    s2 += __shfl_xor(s2, m, 64);
    s3 += __shfl_xor(s3, m, 64);
  }
  if (ch == 0){
    float mx = fmaxf(fmaxf(s0, s1), fmaxf(s2, s3));
    float e0 = __expf(s0 - mx), e1 = __expf(s1 - mx), e2 = __expf(s2 - mx), e3 = __expf(s3 - mx);
    float inv = 1.f / (e0 + e1 + e2 + e3);
    f32x4 g; g[0] = e0 * inv; g[1] = e1 * inv; g[2] = e2 * inv; g[3] = e3 * inv;
    *(f32x4*)(gs + (size_t)row * 4) = g;
  }
}

// ============ G1: T = X(bf16) @ VfT, split-K=4, fp32 atomic accumulate ============
// tile 64(M) x 128(N), BK=32, K-chunk 512. grid (M/64, N/128, 4)
__global__ __launch_bounds__(256) void gemm1_k(const unsigned short* __restrict__ A,
                                               const unsigned short* __restrict__ BT,
                                               float* __restrict__ vxf){
  const int bm0 = blockIdx.x * 64;
  const int bn0 = blockIdx.y * 128;
  const int kc0 = blockIdx.z * 512;
  const int kend = kc0 + 512;
  const int tid = threadIdx.x;
  const int lane = tid & 63;
  const int wv = tid >> 6;
  const int wm = wv >> 1, wn = wv & 1;

  __shared__ unsigned short As[64][40];
  __shared__ unsigned short Bs[128][40];

  f32x4 acc[2][4] = {};
  const int arow = tid >> 2;
  const int aseg = tid & 3;

  u16x8 areg  = *(const u16x8*)(A  + (size_t)(bm0 + arow) * Dd + kc0 + aseg * 8);
  u16x8 breg0 = *(const u16x8*)(BT + (size_t)(bn0 + arow) * Dd + kc0 + aseg * 8);
  u16x8 breg1 = *(const u16x8*)(BT + (size_t)(bn0 + arow + 64) * Dd + kc0 + aseg * 8);

  for (int k0 = kc0; k0 < kend; k0 += 32){
    __syncthreads();
    *(u16x8*)(&As[arow][aseg * 8]) = areg;
    *(u16x8*)(&Bs[arow][aseg * 8]) = breg0;
    *(u16x8*)(&Bs[arow + 64][aseg * 8]) = breg1;
    __syncthreads();
    if (k0 + 32 < kend){
      areg  = *(const u16x8*)(A  + (size_t)(bm0 + arow) * Dd + k0 + 32 + aseg * 8);
      breg0 = *(const u16x8*)(BT + (size_t)(bn0 + arow) * Dd + k0 + 32 + aseg * 8);
      breg1 = *(const u16x8*)(BT + (size_t)(bn0 + arow + 64) * Dd + k0 + 32 + aseg * 8);
    }
    bf16x8 af[2];
    #pragma unroll
    for (int mi = 0; mi < 2; mi++)
      af[mi] = *reinterpret_cast<const bf16x8*>(&As[wm * 32 + mi * 16 + (lane & 15)][(lane >> 4) * 8]);
    #pragma unroll
    for (int nj = 0; nj < 4; nj++){
      bf16x8 bfr = *reinterpret_cast<const bf16x8*>(&Bs[wn * 64 + nj * 16 + (lane & 15)][(lane >> 4) * 8]);
      #pragma unroll
      for (int mi = 0; mi < 2; mi++)
        acc[mi][nj] = __builtin_amdgcn_mfma_f32_16x16x32_bf16(af[mi], bfr, acc[mi][nj], 0, 0, 0);
    }
  }

  #pragma unroll
  for (int mi = 0; mi < 2; mi++)
    #pragma unroll
    for (int nj = 0; nj < 4; nj++)
      #pragma unroll
      for (int q = 0; q < 4; q++){
        int row = bm0 + wm * 32 + mi * 16 + (lane >> 4) * 4 + q;
        int col = bn0 + wn * 64 + nj * 16 + (lane & 15);
        atomicAdd(&vxf[(size_t)row * 256 + col], acc[mi][nj][q]);
      }
}

// ============ G2: CX = tanh(vxf) @ CbT;  wb = bf16(gs * tanh(CX)) ============
// A staged from fp32 with tanh applied. tile 64x128, K=256. grid (M/64, 2)
__global__ __launch_bounds__(256) void gemm2_k(const float* __restrict__ vxf,
                                               const unsigned short* __restrict__ BT,
                                               const float* __restrict__ gs,
                                               unsigned short* __restrict__ wb){
  const int bm0 = blockIdx.x * 64;
  const int bn0 = blockIdx.y * 128;
  const int tid = threadIdx.x;
  const int lane = tid & 63;
  const int wv = tid >> 6;
  const int wm = wv >> 1, wn = wv & 1;

  __shared__ unsigned short As[64][40];
  __shared__ unsigned short Bs[128][40];

  f32x4 acc[2][4] = {};
  const int arow = tid >> 2;
  const int aseg = tid & 3;

  f32x4 a0 = *(const f32x4*)(vxf + (size_t)(bm0 + arow) * 256 + aseg * 8);
  f32x4 a1 = *(const f32x4*)(vxf + (size_t)(bm0 + arow) * 256 + aseg * 8 + 4);
  u16x8 breg0 = *(const u16x8*)(BT + (size_t)(bn0 + arow) * 256 + aseg * 8);
  u16x8 breg1 = *(const u16x8*)(BT + (size_t)(bn0 + arow + 64) * 256 + aseg * 8);

  for (int k0 = 0; k0 < 256; k0 += 32){
    __syncthreads();
    {
      u16x8 av;
      #pragma unroll
      for (int j = 0; j < 4; j++){ av[j] = f2bf(tanhf(a0[j])); av[4 + j] = f2bf(tanhf(a1[j])); }
      *(u16x8*)(&As[arow][aseg * 8]) = av;
    }
    *(u16x8*)(&Bs[arow][aseg * 8]) = breg0;
    *(u16x8*)(&Bs[arow + 64][aseg * 8]) = breg1;
    __syncthreads();
    if (k0 + 32 < 256){
      a0 = *(const f32x4*)(vxf + (size_t)(bm0 + arow) * 256 + k0 + 32 + aseg * 8);
      a1 = *(const f32x4*)(vxf + (size_t)(bm0 + arow) * 256 + k0 + 32 + aseg * 8 + 4);
      breg0 = *(const u16x8*)(BT + (size_t)(bn0 + arow) * 256 + k0 + 32 + aseg * 8);
      breg1 = *(const u16x8*)(BT + (size_t)(bn0 + arow + 64) * 256 + k0 + 32 + aseg * 8);
    }
    bf16x8 af[2];
    #pragma unroll
    for (int mi = 0; mi < 2; mi++)
      af[mi] = *reinterpret_cast<const bf16x8*>(&As[wm * 32 + mi * 16 + (lane & 15)][(lane >> 4) * 8]);
    #pragma unroll
    for (int nj = 0; nj < 4; nj++){
      bf16x8 bfr = *reinterpret_cast<const bf16x8*>(&Bs[wn * 64 + nj * 16 + (lane & 15)][(lane >> 4) * 8]);
      #pragma unroll
      for (int mi = 0; mi < 2; mi++)
        acc[mi][nj] = __builtin_amdgcn_mfma_f32_16x16x32_bf16(af[mi], bfr, acc[mi][nj], 0, 0, 0);
    }
  }

  #pragma unroll
  for (int mi = 0; mi < 2; mi++)
    #pragma unroll
    for (int nj = 0; nj < 4; nj++)
      #pragma unroll
      for (int q = 0; q < 4; q++){
        int row = bm0 + wm * 32 + mi * 16 + (lane >> 4) * 4 + q;
        int col = bn0 + wn * 64 + nj * 16 + (lane & 15);
        float g = gs[(size_t)row * 4 + (col >> 6)];
        wb[(size_t)row * 256 + col] = f2bf(g * tanhf(acc[mi][nj][q]));
      }
}

// ============ G3: Y = wb @ UfT; x_new = x_old + x0*(bias + Y) ============
// tile 64x128, K=256, LDS-staged vectorized epilogue. grid (M/64, D/128)
__global__ __launch_bounds__(256) void gemm3_k(const unsigned short* __restrict__ A,
                                               const unsigned short* __restrict__ BT,
                                               const float* __restrict__ xold,
                                               const unsigned short* __restrict__ x0b,
                                               const float* __restrict__ x0f,
                                               const float* __restrict__ biasrow,
                                               float* __restrict__ out,
                                               unsigned short* __restrict__ xbn){
  const int bm0 = blockIdx.x * 64;
  const int bn0 = blockIdx.y * 128;
  const int tid = threadIdx.x;
  const int lane = tid & 63;
  const int wv = tid >> 6;
  const int wm = wv >> 1, wn = wv & 1;

  __shared__ __align__(16) char smraw[64 * 132 * 4];   // union: As/Bs then epi
  unsigned short (*As)[40] = (unsigned short (*)[40])smraw;            // 5120 B
  unsigned short (*Bs)[40] = (unsigned short (*)[40])(smraw + 5120);   // 10240 B
  float (*epi)[132] = (float (*)[132])smraw;                           // 33792 B

  f32x4 acc[2][4] = {};
  const int arow = tid >> 2;
  const int aseg = tid & 3;

  u16x8 areg  = *(const u16x8*)(A  + (size_t)(bm0 + arow) * 256 + aseg * 8);
  u16x8 breg0 = *(const u16x8*)(BT + (size_t)(bn0 + arow) * 256 + aseg * 8);
  u16x8 breg1 = *(const u16x8*)(BT + (size_t)(bn0 + arow + 64) * 256 + aseg * 8);

  for (int k0 = 0; k0 < 256; k0 += 32){
    __syncthreads();
    *(u16x8*)(&As[arow][aseg * 8]) = areg;
    *(u16x8*)(&Bs[arow][aseg * 8]) = breg0;
    *(u16x8*)(&Bs[arow + 64][aseg * 8]) = breg1;
    __syncthreads();
    if (k0 + 32 < 256){
      areg  = *(const u16x8*)(A  + (size_t)(bm0 + arow) * 256 + k0 + 32 + aseg * 8);
      breg0 = *(const u16x8*)(BT + (size_t)(bn0 + arow) * 256 + k0 + 32 + aseg * 8);
      breg1 = *(const u16x8*)(BT + (size_t)(bn0 + arow + 64) * 256 + k0 + 32 + aseg * 8);
    }
    bf16x8 af[2];
    #pragma unroll
    for (int mi = 0; mi < 2; mi++)
      af[mi] = *reinterpret_cast<const bf16x8*>(&As[wm * 32 + mi * 16 + (lane & 15)][(lane >> 4) * 8]);
    #pragma unroll
    for (int nj = 0; nj < 4; nj++){
      bf16x8 bfr = *reinterpret_cast<const bf16x8*>(&Bs[wn * 64 + nj * 16 + (lane & 15)][(lane >> 4) * 8]);
      #pragma unroll
      for (int mi = 0; mi < 2; mi++)
        acc[mi][nj] = __builtin_amdgcn_mfma_f32_16x16x32_bf16(af[mi], bfr, acc[mi][nj], 0, 0, 0);
    }
  }

  // stage acc -> LDS, then vectorized row-major IO
  __syncthreads();
  #pragma unroll
  for (int mi = 0; mi < 2; mi++)
    #pragma unroll
    for (int nj = 0; nj < 4; nj++)
      #pragma unroll
      for (int q = 0; q < 4; q++){
        int row = wm * 32 + mi * 16 + (lane >> 4) * 4 + q;
        int col = wn * 64 + nj * 16 + (lane & 15);
        epi[row][col] = acc[mi][nj][q];
      }
  __syncthreads();

  #pragma unroll
  for (int c = 0; c < 8; c++){
    int chunk = c * 256 + tid;
    int row = chunk >> 5;
    int col = (chunk & 31) * 4;
    f32x4 y = *(const f32x4*)&epi[row][col];
    size_t o = (size_t)(bm0 + row) * Dd + bn0 + col;
    f32x4 xo = *(const f32x4*)(xold + o);
    f32x4 bv = *(const f32x4*)(biasrow + bn0 + col);
    f32x4 x0v;
    if (x0b){
      u16x4 xv = *(const u16x4*)(x0b + o);
      #pragma unroll
      for (int j = 0; j < 4; j++) x0v[j] = bf2f(xv[j]);
    } else {
      x0v = *(const f32x4*)(x0f + o);
    }
    f32x4 xn;
    #pragma unroll
    for (int j = 0; j < 4; j++) xn[j] = xo[j] + x0v[j] * (bv[j] + y[j]);
    *(f32x4*)(out + o) = xn;
    if (xbn){
      u16x4 xnb;
      #pragma unroll
      for (int j = 0; j < 4; j++) xnb[j] = f2bf(xn[j]);
      *(u16x4*)(xbn + o) = xnb;
    }
  }
}

extern "C" void kernel_launch(void* const* d_in, const int* in_sizes, int n_in,
                              void* d_out, int out_size, void* d_ws, size_t ws_size,
                              hipStream_t stream){
  (void)in_sizes; (void)n_in; (void)out_size;
  const float* inp  = (const float*)d_in[0];
  const float* U    = (const float*)d_in[1];
  const float* V    = (const float*)d_in[2];
  const float* C    = (const float*)d_in[3];
  const float* gw   = (const float*)d_in[4];
  const float* bias = (const float*)d_in[5];
  float* out = (float*)d_out;

  char* ws = (char*)d_ws;
  size_t o = 0;
  unsigned short* xb  = (unsigned short*)(ws + o); o += (size_t)Bb * Dd * 2;       // 33.55 MB
  float*          vxf = (float*)(ws + o);          o += (size_t)Bb * 256 * 4;      //  8.39 MB
  unsigned short* wb  = (unsigned short*)(ws + o); o += (size_t)Bb * 256 * 2;      //  4.19 MB
  float*          gsb = (float*)(ws + o);          o += (size_t)Bb * 4 * 4;        //  0.13 MB
  unsigned short* vft = (unsigned short*)(ws + o); o += (size_t)Ll * 256 * Dd * 2; //  3.15 MB
  unsigned short* uft = (unsigned short*)(ws + o); o += (size_t)Ll * Dd * 256 * 2; //  3.15 MB
  unsigned short* cbt = (unsigned short*)(ws + o); o += (size_t)Ll * 256 * 256 * 2;//  0.39 MB
  unsigned short* g16 = (unsigned short*)(ws + o); o += (size_t)Ee * Dd * 2;       //  0.02 MB
  if (ws_size < o) return;
  // optional bf16 copy of x0 (saves 33.5 MB fp32 read per layer in G3)
  unsigned short* xb0 = nullptr;
  if (ws_size >= o + (size_t)Bb * Dd * 2){
    xb0 = (unsigned short*)(ws + o); o += (size_t)Bb * Dd * 2;                     // 33.55 MB
  }

  cast_x_k<<<2048, 256, 0, stream>>>(inp, xb, xb0);
  prep_w_k<<<2048, 256, 0, stream>>>(U, V, C, gw, vft, uft, cbt, g16);

  for (int l = 0; l < Ll; l++){
    gate_k<<<Bb / 16, 256, 0, stream>>>(xb, g16, gsb);
    zero_k<<<512, 256, 0, stream>>>(vxf, Bb * 256 / 4);
    // G1: vxf += X @ Vf (split-K=4, fp32 atomics)   M=8192 K=2048 N=256
    gemm1_k<<<dim3(Bb / 64, 2, 4), 256, 0, stream>>>(xb, vft + (size_t)l * 256 * Dd, vxf);
    // G2: wb = bf16(gs * tanh(tanh(vxf) @ Cbd))     M=8192 K=256 N=256
    gemm2_k<<<dim3(Bb / 64, 2), 256, 0, stream>>>(vxf, cbt + (size_t)l * 256 * 256, gsb, wb);
    // G3: x_new = x_old + x0*(bias + wb @ Uf)       M=8192 K=256 N=2048
    const float* xold = (l == 0) ? inp : out;
    unsigned short* xbn = (l < Ll - 1) ? xb : nullptr;
    gemm3_k<<<dim3(Bb / 64, Dd / 128), 256, 0, stream>>>(
        wb, uft + (size_t)l * Dd * 256, xold, xb0, inp, bias + (size_t)l * Dd, out, xbn);
  }
}

// Round 3
// 301.191 us; speedup vs baseline: 1.3306x; 1.3098x over previous
//
#include <hip/hip_runtime.h>
#include <cmath>

#define Bb 8192
#define Dd 2048
#define Rr 64
#define Ee 4
#define Ll 3

typedef __bf16 bf16x8 __attribute__((ext_vector_type(8)));
typedef float f32x4 __attribute__((ext_vector_type(4)));
typedef unsigned short u16x8 __attribute__((ext_vector_type(8)));
typedef unsigned short u16x4 __attribute__((ext_vector_type(4)));

__device__ __forceinline__ unsigned short f2bf(float f){
  unsigned u = __builtin_bit_cast(unsigned, f);
  u += 0x7fffu + ((u >> 16) & 1u);
  return (unsigned short)(u >> 16);
}
__device__ __forceinline__ float bf2f(unsigned short h){
  return __builtin_bit_cast(float, ((unsigned)h) << 16);
}

// ---------------- prep: transpose/cast weights ----------------
// VfT[l][n][d] = V[l, e=n/64, d, r=n%64]   (256 x 2048, N-major)
// UfT[l][d][k] = U[l, e=k/64, d, s=k%64]   (2048 x 256, N-major)
// cb16[l][e][s][r] = bf16(C[l,e,s,r])      (direct cast)
// gw16[e][d] = bf16(gate_w[e][d])
__global__ __launch_bounds__(256) void prep_w_k(const float* __restrict__ U,
                                                const float* __restrict__ V,
                                                const float* __restrict__ C,
                                                const float* __restrict__ gw,
                                                unsigned short* __restrict__ VfT,
                                                unsigned short* __restrict__ UfT,
                                                unsigned short* __restrict__ cb16,
                                                unsigned short* __restrict__ gw16){
  const int NV = Ll * 256 * Dd;
  const int NU = Ll * Dd * 256;
  const int NC = Ll * Ee * Rr * Rr;
  const int NG = Ee * Dd;
  const int total = NV + NU + NC + NG;
  for (int idx = blockIdx.x * blockDim.x + threadIdx.x; idx < total; idx += gridDim.x * blockDim.x){
    if (idx < NV){
      int l = idx / (256 * Dd); int rem = idx - l * 256 * Dd;
      int n = rem / Dd, d = rem - n * Dd;
      int e = n >> 6, r = n & 63;
      VfT[idx] = f2bf(V[(((size_t)l * Ee + e) * Dd + d) * Rr + r]);
    } else if (idx < NV + NU){
      int j = idx - NV;
      int l = j / (Dd * 256); int rem = j - l * Dd * 256;
      int d = rem / 256, k = rem - d * 256;
      int e = k >> 6, s = k & 63;
      UfT[j] = f2bf(U[(((size_t)l * Ee + e) * Dd + d) * Rr + s]);
    } else if (idx < NV + NU + NC){
      int j = idx - NV - NU;
      cb16[j] = f2bf(C[j]);
    } else {
      int j = idx - NV - NU - NC;
      gw16[j] = f2bf(gw[j]);
    }
  }
}

// ---------------- gate: logits = x @ gate_w^T, softmax -> gs (B,4) ----------------
template<bool AF32>
__global__ __launch_bounds__(256) void gate_k(const void* __restrict__ xv,
                                              const unsigned short* __restrict__ gw16,
                                              float* __restrict__ gs){
  int tid = threadIdx.x;
  int row = blockIdx.x * 16 + (tid >> 4);
  int ch  = tid & 15;
  const unsigned short* g0 = gw16 + ch * 128;
  float s0 = 0.f, s1 = 0.f, s2 = 0.f, s3 = 0.f;
  for (int j = 0; j < 16; j++){
    float xf8[8];
    if constexpr (AF32){
      const float* xr = (const float*)xv + (size_t)row * Dd + ch * 128;
      f32x4 v0 = *(const f32x4*)(xr + j * 8);
      f32x4 v1 = *(const f32x4*)(xr + j * 8 + 4);
      #pragma unroll
      for (int u = 0; u < 4; u++){ xf8[u] = v0[u]; xf8[4 + u] = v1[u]; }
    } else {
      const unsigned short* xr = (const unsigned short*)xv + (size_t)row * Dd + ch * 128;
      u16x8 xvv = *(const u16x8*)(xr + j * 8);
      #pragma unroll
      for (int u = 0; u < 8; u++) xf8[u] = bf2f(xvv[u]);
    }
    u16x8 g0v = *(const u16x8*)(g0 + 0 * Dd + j * 8);
    u16x8 g1v = *(const u16x8*)(g0 + 1 * Dd + j * 8);
    u16x8 g2v = *(const u16x8*)(g0 + 2 * Dd + j * 8);
    u16x8 g3v = *(const u16x8*)(g0 + 3 * Dd + j * 8);
    #pragma unroll
    for (int u = 0; u < 8; u++){
      s0 += xf8[u] * bf2f(g0v[u]);
      s1 += xf8[u] * bf2f(g1v[u]);
      s2 += xf8[u] * bf2f(g2v[u]);
      s3 += xf8[u] * bf2f(g3v[u]);
    }
  }
  #pragma unroll
  for (int m = 1; m < 16; m <<= 1){
    s0 += __shfl_xor(s0, m, 64);
    s1 += __shfl_xor(s1, m, 64);
    s2 += __shfl_xor(s2, m, 64);
    s3 += __shfl_xor(s3, m, 64);
  }
  if (ch == 0){
    float mx = fmaxf(fmaxf(s0, s1), fmaxf(s2, s3));
    float e0 = __expf(s0 - mx), e1 = __expf(s1 - mx), e2 = __expf(s2 - mx), e3 = __expf(s3 - mx);
    float inv = 1.f / (e0 + e1 + e2 + e3);
    f32x4 g; g[0] = e0 * inv; g[1] = e1 * inv; g[2] = e2 * inv; g[3] = e3 * inv;
    *(f32x4*)(gs + (size_t)row * 4) = g;
  }
}

// ============ G1: T = X @ VfT, split-K=4 into separate fp32 partials ============
// tile 64(M) x 128(N), BK=32, K-chunk 512. grid (M/64, 2, 4). No atomics.
template<bool AF32>
__global__ __launch_bounds__(256) void gemm1_k(const void* __restrict__ Av,
                                               const unsigned short* __restrict__ BT,
                                               float* __restrict__ vxp){
  const int bm0 = blockIdx.x * 64;
  const int bn0 = blockIdx.y * 128;
  const int z   = blockIdx.z;
  const int kc0 = z * 512;
  const int tid = threadIdx.x;
  const int lane = tid & 63;
  const int wv = tid >> 6;
  const int wm = wv >> 1, wn = wv & 1;

  __shared__ __align__(16) char smraw[17408];
  unsigned short (*As)[40] = (unsigned short (*)[40])smraw;            // 5120 B
  unsigned short (*Bs)[40] = (unsigned short (*)[40])(smraw + 5120);   // 10240 B
  float (*epi)[132] = (float (*)[132])smraw;                           // 16896 B (half-tile)

  f32x4 acc[2][4] = {};
  const int arow = tid >> 2;
  const int aseg = tid & 3;

  f32x4 a0, a1; u16x8 areg;
  if constexpr (AF32){
    a0 = *(const f32x4*)((const float*)Av + (size_t)(bm0 + arow) * Dd + kc0 + aseg * 8);
    a1 = *(const f32x4*)((const float*)Av + (size_t)(bm0 + arow) * Dd + kc0 + aseg * 8 + 4);
  } else {
    areg = *(const u16x8*)((const unsigned short*)Av + (size_t)(bm0 + arow) * Dd + kc0 + aseg * 8);
  }
  u16x8 breg0 = *(const u16x8*)(BT + (size_t)(bn0 + arow) * Dd + kc0 + aseg * 8);
  u16x8 breg1 = *(const u16x8*)(BT + (size_t)(bn0 + arow + 64) * Dd + kc0 + aseg * 8);

  for (int k0 = kc0; k0 < kc0 + 512; k0 += 32){
    __syncthreads();
    if constexpr (AF32){
      u16x8 av;
      #pragma unroll
      for (int j = 0; j < 4; j++){ av[j] = f2bf(a0[j]); av[4 + j] = f2bf(a1[j]); }
      *(u16x8*)(&As[arow][aseg * 8]) = av;
    } else {
      *(u16x8*)(&As[arow][aseg * 8]) = areg;
    }
    *(u16x8*)(&Bs[arow][aseg * 8]) = breg0;
    *(u16x8*)(&Bs[arow + 64][aseg * 8]) = breg1;
    __syncthreads();
    if (k0 + 32 < kc0 + 512){
      if constexpr (AF32){
        a0 = *(const f32x4*)((const float*)Av + (size_t)(bm0 + arow) * Dd + k0 + 32 + aseg * 8);
        a1 = *(const f32x4*)((const float*)Av + (size_t)(bm0 + arow) * Dd + k0 + 32 + aseg * 8 + 4);
      } else {
        areg = *(const u16x8*)((const unsigned short*)Av + (size_t)(bm0 + arow) * Dd + k0 + 32 + aseg * 8);
      }
      breg0 = *(const u16x8*)(BT + (size_t)(bn0 + arow) * Dd + k0 + 32 + aseg * 8);
      breg1 = *(const u16x8*)(BT + (size_t)(bn0 + arow + 64) * Dd + k0 + 32 + aseg * 8);
    }
    bf16x8 af[2];
    #pragma unroll
    for (int mi = 0; mi < 2; mi++)
      af[mi] = *reinterpret_cast<const bf16x8*>(&As[wm * 32 + mi * 16 + (lane & 15)][(lane >> 4) * 8]);
    #pragma unroll
    for (int nj = 0; nj < 4; nj++){
      bf16x8 bfr = *reinterpret_cast<const bf16x8*>(&Bs[wn * 64 + nj * 16 + (lane & 15)][(lane >> 4) * 8]);
      #pragma unroll
      for (int mi = 0; mi < 2; mi++)
        acc[mi][nj] = __builtin_amdgcn_mfma_f32_16x16x32_bf16(af[mi], bfr, acc[mi][nj], 0, 0, 0);
    }
  }

  // half-tile LDS-staged fp32 partial store
  float* outz = vxp + (size_t)z * Bb * 256;
  #pragma unroll
  for (int h = 0; h < 2; h++){
    __syncthreads();
    if (wm == h){
      #pragma unroll
      for (int mi = 0; mi < 2; mi++)
        #pragma unroll
        for (int nj = 0; nj < 4; nj++)
          #pragma unroll
          for (int q = 0; q < 4; q++)
            epi[mi * 16 + (lane >> 4) * 4 + q][wn * 64 + nj * 16 + (lane & 15)] = acc[mi][nj][q];
    }
    __syncthreads();
    #pragma unroll
    for (int c = 0; c < 4; c++){
      int idx = c * 256 + tid;
      int r = idx >> 5;
      int col = (idx & 31) * 4;
      *(f32x4*)(outz + (size_t)(bm0 + h * 32 + r) * 256 + bn0 + col) = *(const f32x4*)&epi[r][col];
    }
  }
}

// ============ G2: block-diag C. Expert e needs only K in [64e, 64e+64) ============
// grid (M/64, 4=experts). A-staging sums 4 partials + tanh. wb = bf16(gs*tanh(cx)).
__global__ __launch_bounds__(256) void gemm2_k(const float* __restrict__ vxp,
                                               const unsigned short* __restrict__ cb,
                                               const float* __restrict__ gs,
                                               unsigned short* __restrict__ wb){
  const int bm0 = blockIdx.x * 64;
  const int e   = blockIdx.y;
  const int tid = threadIdx.x;
  const int lane = tid & 63;
  const int wv = tid >> 6;
  const int wm = wv >> 1, wn = wv & 1;

  __shared__ __align__(16) char smraw[18432];
  unsigned short (*As)[72] = (unsigned short (*)[72])smraw;            // 9216 B
  unsigned short (*Bs)[72] = (unsigned short (*)[72])(smraw + 9216);   // 9216 B
  unsigned short (*epi)[72] = (unsigned short (*)[72])smraw;           // union over As

  const int arow = tid >> 2;
  const int aseg = tid & 3;

  // A: sum 4 partials + tanh -> bf16 LDS (rows 0..63, k 0..63 within expert block)
  f32x4 t[4];
  #pragma unroll
  for (int j = 0; j < 4; j++)
    t[j] = *(const f32x4*)(vxp + (size_t)(bm0 + arow) * 256 + e * 64 + aseg * 16 + j * 4);
  #pragma unroll
  for (int z = 1; z < 4; z++)
    #pragma unroll
    for (int j = 0; j < 4; j++)
      t[j] += *(const f32x4*)(vxp + (size_t)z * Bb * 256 + (size_t)(bm0 + arow) * 256 + e * 64 + aseg * 16 + j * 4);
  u16x8 av0, av1;
  #pragma unroll
  for (int j = 0; j < 4; j++){
    av0[j] = f2bf(tanhf(t[0][j])); av0[4 + j] = f2bf(tanhf(t[1][j]));
    av1[j] = f2bf(tanhf(t[2][j])); av1[4 + j] = f2bf(tanhf(t[3][j]));
  }
  *(u16x8*)(&As[arow][aseg * 16]) = av0;
  *(u16x8*)(&As[arow][aseg * 16 + 8]) = av1;
  // B: C[e] rows s, cols r (direct)
  *(u16x8*)(&Bs[arow][aseg * 16])     = *(const u16x8*)(cb + e * 4096 + arow * 64 + aseg * 16);
  *(u16x8*)(&Bs[arow][aseg * 16 + 8]) = *(const u16x8*)(cb + e * 4096 + arow * 64 + aseg * 16 + 8);
  __syncthreads();

  f32x4 acc[2][2] = {};
  #pragma unroll
  for (int kk = 0; kk < 2; kk++){
    bf16x8 af[2];
    #pragma unroll
    for (int mi = 0; mi < 2; mi++)
      af[mi] = *reinterpret_cast<const bf16x8*>(&As[wm * 32 + mi * 16 + (lane & 15)][kk * 32 + (lane >> 4) * 8]);
    #pragma unroll
    for (int nj = 0; nj < 2; nj++){
      bf16x8 bfr = *reinterpret_cast<const bf16x8*>(&Bs[wn * 32 + nj * 16 + (lane & 15)][kk * 32 + (lane >> 4) * 8]);
      #pragma unroll
      for (int mi = 0; mi < 2; mi++)
        acc[mi][nj] = __builtin_amdgcn_mfma_f32_16x16x32_bf16(af[mi], bfr, acc[mi][nj], 0, 0, 0);
    }
  }

  __syncthreads();
  #pragma unroll
  for (int mi = 0; mi < 2; mi++)
    #pragma unroll
    for (int nj = 0; nj < 2; nj++)
      #pragma unroll
      for (int q = 0; q < 4; q++){
        int row = wm * 32 + mi * 16 + (lane >> 4) * 4 + q;
        int col = wn * 32 + nj * 16 + (lane & 15);
        float g = gs[(size_t)(bm0 + row) * 4 + e];
        epi[row][col] = f2bf(g * tanhf(acc[mi][nj][q]));
      }
  __syncthreads();
  #pragma unroll
  for (int c = 0; c < 2; c++){
    int idx = c * 256 + tid;
    int row = idx >> 3;
    int col = (idx & 7) * 8;
    *(u16x8*)(wb + (size_t)(bm0 + row) * 256 + e * 64 + col) = *(const u16x8*)(&epi[row][col]);
  }
}

// ============ G3: Y = wb @ UfT; x_new = x_old + x0*(bias + Y) ============
// tile 64x128, K=256, half-tile LDS epilogue (17 KB -> 8 blocks/CU). grid (M/64, D/128)
__global__ __launch_bounds__(256) void gemm3_k(const unsigned short* __restrict__ A,
                                               const unsigned short* __restrict__ BT,
                                               const float* __restrict__ xold,
                                               const float* __restrict__ x0f,
                                               const float* __restrict__ biasrow,
                                               float* __restrict__ out,
                                               unsigned short* __restrict__ xbn){
  const int bm0 = blockIdx.x * 64;
  const int bn0 = blockIdx.y * 128;
  const int tid = threadIdx.x;
  const int lane = tid & 63;
  const int wv = tid >> 6;
  const int wm = wv >> 1, wn = wv & 1;

  __shared__ __align__(16) char smraw[17408];
  unsigned short (*As)[40] = (unsigned short (*)[40])smraw;            // 5120 B
  unsigned short (*Bs)[40] = (unsigned short (*)[40])(smraw + 5120);   // 10240 B
  float (*epi)[132] = (float (*)[132])smraw;                           // 16896 B (half)

  f32x4 acc[2][4] = {};
  const int arow = tid >> 2;
  const int aseg = tid & 3;

  u16x8 areg  = *(const u16x8*)(A  + (size_t)(bm0 + arow) * 256 + aseg * 8);
  u16x8 breg0 = *(const u16x8*)(BT + (size_t)(bn0 + arow) * 256 + aseg * 8);
  u16x8 breg1 = *(const u16x8*)(BT + (size_t)(bn0 + arow + 64) * 256 + aseg * 8);

  for (int k0 = 0; k0 < 256; k0 += 32){
    __syncthreads();
    *(u16x8*)(&As[arow][aseg * 8]) = areg;
    *(u16x8*)(&Bs[arow][aseg * 8]) = breg0;
    *(u16x8*)(&Bs[arow + 64][aseg * 8]) = breg1;
    __syncthreads();
    if (k0 + 32 < 256){
      areg  = *(const u16x8*)(A  + (size_t)(bm0 + arow) * 256 + k0 + 32 + aseg * 8);
      breg0 = *(const u16x8*)(BT + (size_t)(bn0 + arow) * 256 + k0 + 32 + aseg * 8);
      breg1 = *(const u16x8*)(BT + (size_t)(bn0 + arow + 64) * 256 + k0 + 32 + aseg * 8);
    }
    bf16x8 af[2];
    #pragma unroll
    for (int mi = 0; mi < 2; mi++)
      af[mi] = *reinterpret_cast<const bf16x8*>(&As[wm * 32 + mi * 16 + (lane & 15)][(lane >> 4) * 8]);
    #pragma unroll
    for (int nj = 0; nj < 4; nj++){
      bf16x8 bfr = *reinterpret_cast<const bf16x8*>(&Bs[wn * 64 + nj * 16 + (lane & 15)][(lane >> 4) * 8]);
      #pragma unroll
      for (int mi = 0; mi < 2; mi++)
        acc[mi][nj] = __builtin_amdgcn_mfma_f32_16x16x32_bf16(af[mi], bfr, acc[mi][nj], 0, 0, 0);
    }
  }

  #pragma unroll
  for (int h = 0; h < 2; h++){
    __syncthreads();
    if (wm == h){
      #pragma unroll
      for (int mi = 0; mi < 2; mi++)
        #pragma unroll
        for (int nj = 0; nj < 4; nj++)
          #pragma unroll
          for (int q = 0; q < 4; q++)
            epi[mi * 16 + (lane >> 4) * 4 + q][wn * 64 + nj * 16 + (lane & 15)] = acc[mi][nj][q];
    }
    __syncthreads();
    #pragma unroll
    for (int c = 0; c < 4; c++){
      int idx = c * 256 + tid;
      int r = idx >> 5;
      int col = (idx & 31) * 4;
      int row = bm0 + h * 32 + r;
      f32x4 y = *(const f32x4*)&epi[r][col];
      size_t o = (size_t)row * Dd + bn0 + col;
      f32x4 xo  = *(const f32x4*)(xold + o);
      f32x4 x0v = *(const f32x4*)(x0f + o);
      f32x4 bv  = *(const f32x4*)(biasrow + bn0 + col);
      f32x4 xn;
      #pragma unroll
      for (int j = 0; j < 4; j++) xn[j] = xo[j] + x0v[j] * (bv[j] + y[j]);
      *(f32x4*)(out + o) = xn;
      if (xbn){
        u16x4 xnb;
        #pragma unroll
        for (int j = 0; j < 4; j++) xnb[j] = f2bf(xn[j]);
        *(u16x4*)(xbn + o) = xnb;
      }
    }
  }
}

extern "C" void kernel_launch(void* const* d_in, const int* in_sizes, int n_in,
                              void* d_out, int out_size, void* d_ws, size_t ws_size,
                              hipStream_t stream){
  (void)in_sizes; (void)n_in; (void)out_size;
  const float* inp  = (const float*)d_in[0];
  const float* U    = (const float*)d_in[1];
  const float* V    = (const float*)d_in[2];
  const float* C    = (const float*)d_in[3];
  const float* gw   = (const float*)d_in[4];
  const float* bias = (const float*)d_in[5];
  float* out = (float*)d_out;

  char* ws = (char*)d_ws;
  size_t o = 0;
  unsigned short* xb  = (unsigned short*)(ws + o); o += (size_t)Bb * Dd * 2;        // 33.55 MB
  float*          vxp = (float*)(ws + o);          o += (size_t)4 * Bb * 256 * 4;   // 33.55 MB
  unsigned short* wb  = (unsigned short*)(ws + o); o += (size_t)Bb * 256 * 2;       //  4.19 MB
  float*          gsb = (float*)(ws + o);          o += (size_t)Bb * 4 * 4;         //  0.13 MB
  unsigned short* vft = (unsigned short*)(ws + o); o += (size_t)Ll * 256 * Dd * 2;  //  3.15 MB
  unsigned short* uft = (unsigned short*)(ws + o); o += (size_t)Ll * Dd * 256 * 2;  //  3.15 MB
  unsigned short* cb16= (unsigned short*)(ws + o); o += (size_t)Ll * Ee * Rr * Rr * 2; // 0.10 MB
  unsigned short* g16 = (unsigned short*)(ws + o); o += (size_t)Ee * Dd * 2;        //  0.02 MB
  if (ws_size < o) return;

  prep_w_k<<<1024, 256, 0, stream>>>(U, V, C, gw, vft, uft, cb16, g16);

  for (int l = 0; l < Ll; l++){
    if (l == 0){
      gate_k<true><<<Bb / 16, 256, 0, stream>>>(inp, g16, gsb);
      gemm1_k<true><<<dim3(Bb / 64, 2, 4), 256, 0, stream>>>(inp, vft + (size_t)l * 256 * Dd, vxp);
    } else {
      gate_k<false><<<Bb / 16, 256, 0, stream>>>(xb, g16, gsb);
      gemm1_k<false><<<dim3(Bb / 64, 2, 4), 256, 0, stream>>>(xb, vft + (size_t)l * 256 * Dd, vxp);
    }
    gemm2_k<<<dim3(Bb / 64, Ee), 256, 0, stream>>>(vxp, cb16 + (size_t)l * Ee * Rr * Rr, gsb, wb);
    const float* xold = (l == 0) ? inp : out;
    unsigned short* xbn = (l < Ll - 1) ? xb : nullptr;
    gemm3_k<<<dim3(Bb / 64, Dd / 128), 256, 0, stream>>>(
        wb, uft + (size_t)l * Dd * 256, xold, inp, bias + (size_t)l * Dd, out, xbn);
  }
}

// Round 4
// 274.195 us; speedup vs baseline: 1.4616x; 1.0985x over previous
//
#include <hip/hip_runtime.h>
#include <cmath>

#define Bb 8192
#define Dd 2048
#define Rr 64
#define Ee 4
#define Ll 3

typedef __bf16 bf16x8 __attribute__((ext_vector_type(8)));
typedef float f32x4 __attribute__((ext_vector_type(4)));
typedef unsigned short u16x8 __attribute__((ext_vector_type(8)));
typedef unsigned short u16x4 __attribute__((ext_vector_type(4)));

__device__ __forceinline__ unsigned short f2bf(float f){
  unsigned u = __builtin_bit_cast(unsigned, f);
  u += 0x7fffu + ((u >> 16) & 1u);
  return (unsigned short)(u >> 16);
}
__device__ __forceinline__ float bf2f(unsigned short h){
  return __builtin_bit_cast(float, ((unsigned)h) << 16);
}

// ---------------- prep: transpose/cast weights ----------------
__global__ __launch_bounds__(256) void prep_w_k(const float* __restrict__ U,
                                                const float* __restrict__ V,
                                                const float* __restrict__ C,
                                                const float* __restrict__ gw,
                                                unsigned short* __restrict__ VfT,
                                                unsigned short* __restrict__ UfT,
                                                unsigned short* __restrict__ cb16,
                                                unsigned short* __restrict__ gw16){
  const int NV = Ll * 256 * Dd;
  const int NU = Ll * Dd * 256;
  const int NC = Ll * Ee * Rr * Rr;
  const int NG = Ee * Dd;
  const int total = NV + NU + NC + NG;
  for (int idx = blockIdx.x * blockDim.x + threadIdx.x; idx < total; idx += gridDim.x * blockDim.x){
    if (idx < NV){
      int l = idx / (256 * Dd); int rem = idx - l * 256 * Dd;
      int n = rem / Dd, d = rem - n * Dd;
      int e = n >> 6, r = n & 63;
      VfT[idx] = f2bf(V[(((size_t)l * Ee + e) * Dd + d) * Rr + r]);
    } else if (idx < NV + NU){
      int j = idx - NV;
      int l = j / (Dd * 256); int rem = j - l * Dd * 256;
      int d = rem / 256, k = rem - d * 256;
      int e = k >> 6, s = k & 63;
      UfT[j] = f2bf(U[(((size_t)l * Ee + e) * Dd + d) * Rr + s]);
    } else if (idx < NV + NU + NC){
      int j = idx - NV - NU;
      cb16[j] = f2bf(C[j]);
    } else {
      int j = idx - NV - NU - NC;
      gw16[j] = f2bf(gw[j]);
    }
  }
}

// ---------------- gate: logits = x @ gate_w^T, softmax -> gs (B,4) ----------------
template<bool AF32>
__global__ __launch_bounds__(256) void gate_k(const void* __restrict__ xv,
                                              const unsigned short* __restrict__ gw16,
                                              float* __restrict__ gs){
  int tid = threadIdx.x;
  int row = blockIdx.x * 16 + (tid >> 4);
  int ch  = tid & 15;
  const unsigned short* g0 = gw16 + ch * 128;
  float s0 = 0.f, s1 = 0.f, s2 = 0.f, s3 = 0.f;
  for (int j = 0; j < 16; j++){
    float xf8[8];
    if constexpr (AF32){
      const float* xr = (const float*)xv + (size_t)row * Dd + ch * 128;
      f32x4 v0 = *(const f32x4*)(xr + j * 8);
      f32x4 v1 = *(const f32x4*)(xr + j * 8 + 4);
      #pragma unroll
      for (int u = 0; u < 4; u++){ xf8[u] = v0[u]; xf8[4 + u] = v1[u]; }
    } else {
      const unsigned short* xr = (const unsigned short*)xv + (size_t)row * Dd + ch * 128;
      u16x8 xvv = *(const u16x8*)(xr + j * 8);
      #pragma unroll
      for (int u = 0; u < 8; u++) xf8[u] = bf2f(xvv[u]);
    }
    u16x8 g0v = *(const u16x8*)(g0 + 0 * Dd + j * 8);
    u16x8 g1v = *(const u16x8*)(g0 + 1 * Dd + j * 8);
    u16x8 g2v = *(const u16x8*)(g0 + 2 * Dd + j * 8);
    u16x8 g3v = *(const u16x8*)(g0 + 3 * Dd + j * 8);
    #pragma unroll
    for (int u = 0; u < 8; u++){
      s0 += xf8[u] * bf2f(g0v[u]);
      s1 += xf8[u] * bf2f(g1v[u]);
      s2 += xf8[u] * bf2f(g2v[u]);
      s3 += xf8[u] * bf2f(g3v[u]);
    }
  }
  #pragma unroll
  for (int m = 1; m < 16; m <<= 1){
    s0 += __shfl_xor(s0, m, 64);
    s1 += __shfl_xor(s1, m, 64);
    s2 += __shfl_xor(s2, m, 64);
    s3 += __shfl_xor(s3, m, 64);
  }
  if (ch == 0){
    float mx = fmaxf(fmaxf(s0, s1), fmaxf(s2, s3));
    float e0 = __expf(s0 - mx), e1 = __expf(s1 - mx), e2 = __expf(s2 - mx), e3 = __expf(s3 - mx);
    float inv = 1.f / (e0 + e1 + e2 + e3);
    f32x4 g; g[0] = e0 * inv; g[1] = e1 * inv; g[2] = e2 * inv; g[3] = e3 * inv;
    *(f32x4*)(gs + (size_t)row * 4) = g;
  }
}

// ============ G1: T = X @ VfT, split-K=4, separate fp32 partials, BK=64 ============
// tile 64(M) x 128(N). grid (M/64, 2, 4). Reg-prefetch next K-step.
template<bool AF32>
__global__ __launch_bounds__(256) void gemm1_k(const void* __restrict__ Av,
                                               const unsigned short* __restrict__ BT,
                                               float* __restrict__ vxp){
  const int bm0 = blockIdx.x * 64;
  const int bn0 = blockIdx.y * 128;
  const int z   = blockIdx.z;
  const int kc0 = z * 512;
  const int tid = threadIdx.x;
  const int lane = tid & 63;
  const int wv = tid >> 6;
  const int wm = wv >> 1, wn = wv & 1;

  __shared__ __align__(16) char smraw[27648];
  unsigned short (*As)[72] = (unsigned short (*)[72])smraw;            // 9216 B
  unsigned short (*Bs)[72] = (unsigned short (*)[72])(smraw + 9216);   // 18432 B
  float (*epi)[132] = (float (*)[132])smraw;                           // 16896 B (half-tile)

  f32x4 acc[2][4] = {};
  const int arow = tid >> 2;   // 0..63
  const int aseg = tid & 3;    // 0..3, 16 bf16 each

  const float* Af = (const float*)Av;
  const unsigned short* Ab = (const unsigned short*)Av;

  f32x4 a4[4]; u16x8 ar[2]; u16x8 br[4];
  if constexpr (AF32){
    #pragma unroll
    for (int j = 0; j < 4; j++)
      a4[j] = *(const f32x4*)(Af + (size_t)(bm0 + arow) * Dd + kc0 + aseg * 16 + j * 4);
  } else {
    ar[0] = *(const u16x8*)(Ab + (size_t)(bm0 + arow) * Dd + kc0 + aseg * 16);
    ar[1] = *(const u16x8*)(Ab + (size_t)(bm0 + arow) * Dd + kc0 + aseg * 16 + 8);
  }
  br[0] = *(const u16x8*)(BT + (size_t)(bn0 + arow) * Dd + kc0 + aseg * 16);
  br[1] = *(const u16x8*)(BT + (size_t)(bn0 + arow) * Dd + kc0 + aseg * 16 + 8);
  br[2] = *(const u16x8*)(BT + (size_t)(bn0 + arow + 64) * Dd + kc0 + aseg * 16);
  br[3] = *(const u16x8*)(BT + (size_t)(bn0 + arow + 64) * Dd + kc0 + aseg * 16 + 8);

  for (int k0 = kc0; k0 < kc0 + 512; k0 += 64){
    __syncthreads();
    if constexpr (AF32){
      u16x8 av0, av1;
      #pragma unroll
      for (int j = 0; j < 4; j++){
        av0[j] = f2bf(a4[0][j]); av0[4 + j] = f2bf(a4[1][j]);
        av1[j] = f2bf(a4[2][j]); av1[4 + j] = f2bf(a4[3][j]);
      }
      *(u16x8*)(&As[arow][aseg * 16])     = av0;
      *(u16x8*)(&As[arow][aseg * 16 + 8]) = av1;
    } else {
      *(u16x8*)(&As[arow][aseg * 16])     = ar[0];
      *(u16x8*)(&As[arow][aseg * 16 + 8]) = ar[1];
    }
    *(u16x8*)(&Bs[arow][aseg * 16])          = br[0];
    *(u16x8*)(&Bs[arow][aseg * 16 + 8])      = br[1];
    *(u16x8*)(&Bs[arow + 64][aseg * 16])     = br[2];
    *(u16x8*)(&Bs[arow + 64][aseg * 16 + 8]) = br[3];
    __syncthreads();

    int kn = k0 + 64;
    if (kn < kc0 + 512){
      if constexpr (AF32){
        #pragma unroll
        for (int j = 0; j < 4; j++)
          a4[j] = *(const f32x4*)(Af + (size_t)(bm0 + arow) * Dd + kn + aseg * 16 + j * 4);
      } else {
        ar[0] = *(const u16x8*)(Ab + (size_t)(bm0 + arow) * Dd + kn + aseg * 16);
        ar[1] = *(const u16x8*)(Ab + (size_t)(bm0 + arow) * Dd + kn + aseg * 16 + 8);
      }
      br[0] = *(const u16x8*)(BT + (size_t)(bn0 + arow) * Dd + kn + aseg * 16);
      br[1] = *(const u16x8*)(BT + (size_t)(bn0 + arow) * Dd + kn + aseg * 16 + 8);
      br[2] = *(const u16x8*)(BT + (size_t)(bn0 + arow + 64) * Dd + kn + aseg * 16);
      br[3] = *(const u16x8*)(BT + (size_t)(bn0 + arow + 64) * Dd + kn + aseg * 16 + 8);
    }

    #pragma unroll
    for (int ks = 0; ks < 2; ks++){
      bf16x8 af[2];
      #pragma unroll
      for (int mi = 0; mi < 2; mi++)
        af[mi] = *reinterpret_cast<const bf16x8*>(&As[wm * 32 + mi * 16 + (lane & 15)][ks * 32 + (lane >> 4) * 8]);
      #pragma unroll
      for (int nj = 0; nj < 4; nj++){
        bf16x8 bfr = *reinterpret_cast<const bf16x8*>(&Bs[wn * 64 + nj * 16 + (lane & 15)][ks * 32 + (lane >> 4) * 8]);
        #pragma unroll
        for (int mi = 0; mi < 2; mi++)
          acc[mi][nj] = __builtin_amdgcn_mfma_f32_16x16x32_bf16(af[mi], bfr, acc[mi][nj], 0, 0, 0);
      }
    }
  }

  // half-tile LDS-staged fp32 partial store
  float* outz = vxp + (size_t)z * Bb * 256;
  #pragma unroll
  for (int h = 0; h < 2; h++){
    __syncthreads();
    if (wm == h){
      #pragma unroll
      for (int mi = 0; mi < 2; mi++)
        #pragma unroll
        for (int nj = 0; nj < 4; nj++)
          #pragma unroll
          for (int q = 0; q < 4; q++)
            epi[mi * 16 + (lane >> 4) * 4 + q][wn * 64 + nj * 16 + (lane & 15)] = acc[mi][nj][q];
    }
    __syncthreads();
    #pragma unroll
    for (int c = 0; c < 4; c++){
      int idx = c * 256 + tid;
      int r = idx >> 5;
      int col = (idx & 31) * 4;
      *(f32x4*)(outz + (size_t)(bm0 + h * 32 + r) * 256 + bn0 + col) = *(const f32x4*)&epi[r][col];
    }
  }
}

// ============ G2: block-diag C. Expert e needs only K in [64e, 64e+64) ============
__global__ __launch_bounds__(256) void gemm2_k(const float* __restrict__ vxp,
                                               const unsigned short* __restrict__ cb,
                                               const float* __restrict__ gs,
                                               unsigned short* __restrict__ wb){
  const int bm0 = blockIdx.x * 64;
  const int e   = blockIdx.y;
  const int tid = threadIdx.x;
  const int lane = tid & 63;
  const int wv = tid >> 6;
  const int wm = wv >> 1, wn = wv & 1;

  __shared__ __align__(16) char smraw[18432];
  unsigned short (*As)[72] = (unsigned short (*)[72])smraw;
  unsigned short (*Bs)[72] = (unsigned short (*)[72])(smraw + 9216);
  unsigned short (*epi)[72] = (unsigned short (*)[72])smraw;

  const int arow = tid >> 2;
  const int aseg = tid & 3;

  f32x4 t[4];
  #pragma unroll
  for (int j = 0; j < 4; j++)
    t[j] = *(const f32x4*)(vxp + (size_t)(bm0 + arow) * 256 + e * 64 + aseg * 16 + j * 4);
  #pragma unroll
  for (int z = 1; z < 4; z++)
    #pragma unroll
    for (int j = 0; j < 4; j++)
      t[j] += *(const f32x4*)(vxp + (size_t)z * Bb * 256 + (size_t)(bm0 + arow) * 256 + e * 64 + aseg * 16 + j * 4);
  u16x8 av0, av1;
  #pragma unroll
  for (int j = 0; j < 4; j++){
    av0[j] = f2bf(tanhf(t[0][j])); av0[4 + j] = f2bf(tanhf(t[1][j]));
    av1[j] = f2bf(tanhf(t[2][j])); av1[4 + j] = f2bf(tanhf(t[3][j]));
  }
  *(u16x8*)(&As[arow][aseg * 16]) = av0;
  *(u16x8*)(&As[arow][aseg * 16 + 8]) = av1;
  *(u16x8*)(&Bs[arow][aseg * 16])     = *(const u16x8*)(cb + e * 4096 + arow * 64 + aseg * 16);
  *(u16x8*)(&Bs[arow][aseg * 16 + 8]) = *(const u16x8*)(cb + e * 4096 + arow * 64 + aseg * 16 + 8);
  __syncthreads();

  f32x4 acc[2][2] = {};
  #pragma unroll
  for (int kk = 0; kk < 2; kk++){
    bf16x8 af[2];
    #pragma unroll
    for (int mi = 0; mi < 2; mi++)
      af[mi] = *reinterpret_cast<const bf16x8*>(&As[wm * 32 + mi * 16 + (lane & 15)][kk * 32 + (lane >> 4) * 8]);
    #pragma unroll
    for (int nj = 0; nj < 2; nj++){
      bf16x8 bfr = *reinterpret_cast<const bf16x8*>(&Bs[wn * 32 + nj * 16 + (lane & 15)][kk * 32 + (lane >> 4) * 8]);
      #pragma unroll
      for (int mi = 0; mi < 2; mi++)
        acc[mi][nj] = __builtin_amdgcn_mfma_f32_16x16x32_bf16(af[mi], bfr, acc[mi][nj], 0, 0, 0);
    }
  }

  __syncthreads();
  #pragma unroll
  for (int mi = 0; mi < 2; mi++)
    #pragma unroll
    for (int nj = 0; nj < 2; nj++)
      #pragma unroll
      for (int q = 0; q < 4; q++){
        int row = wm * 32 + mi * 16 + (lane >> 4) * 4 + q;
        int col = wn * 32 + nj * 16 + (lane & 15);
        float g = gs[(size_t)(bm0 + row) * 4 + e];
        epi[row][col] = f2bf(g * tanhf(acc[mi][nj][q]));
      }
  __syncthreads();
  #pragma unroll
  for (int c = 0; c < 2; c++){
    int idx = c * 256 + tid;
    int row = idx >> 3;
    int col = (idx & 7) * 8;
    *(u16x8*)(wb + (size_t)(bm0 + row) * 256 + e * 64 + col) = *(const u16x8*)(&epi[row][col]);
  }
}

// ============ G3: Y = wb @ UfT; x_new = x_old + x0*(bias + Y), bf16 state ============
// MODE 0: xold = x0 (inp f32), write bf16 state    (layer 0)
// MODE 1: xold = bf16 state, in-place RMW           (layer 1)
// MODE 2: xold = bf16 state, write fp32 out only    (layer 2)
template<int MODE>
__global__ __launch_bounds__(256) void gemm3_k(const unsigned short* __restrict__ A,
                                               const unsigned short* __restrict__ BT,
                                               const float* __restrict__ x0f,
                                               unsigned short* __restrict__ xst,
                                               const float* __restrict__ biasrow,
                                               float* __restrict__ out){
  const int bm0 = blockIdx.x * 64;
  const int bn0 = blockIdx.y * 128;
  const int tid = threadIdx.x;
  const int lane = tid & 63;
  const int wv = tid >> 6;
  const int wm = wv >> 1, wn = wv & 1;

  __shared__ __align__(16) char smraw[17408];
  unsigned short (*As)[40] = (unsigned short (*)[40])smraw;            // 5120 B
  unsigned short (*Bs)[40] = (unsigned short (*)[40])(smraw + 5120);   // 10240 B
  float (*epi)[132] = (float (*)[132])smraw;                           // 16896 B (half)

  f32x4 acc[2][4] = {};
  const int arow = tid >> 2;
  const int aseg = tid & 3;

  u16x8 areg  = *(const u16x8*)(A  + (size_t)(bm0 + arow) * 256 + aseg * 8);
  u16x8 breg0 = *(const u16x8*)(BT + (size_t)(bn0 + arow) * 256 + aseg * 8);
  u16x8 breg1 = *(const u16x8*)(BT + (size_t)(bn0 + arow + 64) * 256 + aseg * 8);

  for (int k0 = 0; k0 < 256; k0 += 32){
    __syncthreads();
    *(u16x8*)(&As[arow][aseg * 8]) = areg;
    *(u16x8*)(&Bs[arow][aseg * 8]) = breg0;
    *(u16x8*)(&Bs[arow + 64][aseg * 8]) = breg1;
    __syncthreads();
    if (k0 + 32 < 256){
      areg  = *(const u16x8*)(A  + (size_t)(bm0 + arow) * 256 + k0 + 32 + aseg * 8);
      breg0 = *(const u16x8*)(BT + (size_t)(bn0 + arow) * 256 + k0 + 32 + aseg * 8);
      breg1 = *(const u16x8*)(BT + (size_t)(bn0 + arow + 64) * 256 + k0 + 32 + aseg * 8);
    }
    bf16x8 af[2];
    #pragma unroll
    for (int mi = 0; mi < 2; mi++)
      af[mi] = *reinterpret_cast<const bf16x8*>(&As[wm * 32 + mi * 16 + (lane & 15)][(lane >> 4) * 8]);
    #pragma unroll
    for (int nj = 0; nj < 4; nj++){
      bf16x8 bfr = *reinterpret_cast<const bf16x8*>(&Bs[wn * 64 + nj * 16 + (lane & 15)][(lane >> 4) * 8]);
      #pragma unroll
      for (int mi = 0; mi < 2; mi++)
        acc[mi][nj] = __builtin_amdgcn_mfma_f32_16x16x32_bf16(af[mi], bfr, acc[mi][nj], 0, 0, 0);
    }
  }

  #pragma unroll
  for (int h = 0; h < 2; h++){
    __syncthreads();
    if (wm == h){
      #pragma unroll
      for (int mi = 0; mi < 2; mi++)
        #pragma unroll
        for (int nj = 0; nj < 4; nj++)
          #pragma unroll
          for (int q = 0; q < 4; q++)
            epi[mi * 16 + (lane >> 4) * 4 + q][wn * 64 + nj * 16 + (lane & 15)] = acc[mi][nj][q];
    }
    __syncthreads();
    #pragma unroll
    for (int c = 0; c < 4; c++){
      int idx = c * 256 + tid;
      int r = idx >> 5;
      int col = (idx & 31) * 4;
      int row = bm0 + h * 32 + r;
      size_t o = (size_t)row * Dd + bn0 + col;
      f32x4 y = *(const f32x4*)&epi[r][col];
      f32x4 x0v = *(const f32x4*)(x0f + o);
      f32x4 bv  = *(const f32x4*)(biasrow + bn0 + col);
      f32x4 xo;
      if constexpr (MODE == 0){
        xo = x0v;
      } else {
        u16x4 xv = *(const u16x4*)(xst + o);
        #pragma unroll
        for (int j = 0; j < 4; j++) xo[j] = bf2f(xv[j]);
      }
      f32x4 xn;
      #pragma unroll
      for (int j = 0; j < 4; j++) xn[j] = xo[j] + x0v[j] * (bv[j] + y[j]);
      if constexpr (MODE == 2){
        *(f32x4*)(out + o) = xn;
      } else {
        u16x4 xnb;
        #pragma unroll
        for (int j = 0; j < 4; j++) xnb[j] = f2bf(xn[j]);
        *(u16x4*)(xst + o) = xnb;
      }
    }
  }
}

extern "C" void kernel_launch(void* const* d_in, const int* in_sizes, int n_in,
                              void* d_out, int out_size, void* d_ws, size_t ws_size,
                              hipStream_t stream){
  (void)in_sizes; (void)n_in; (void)out_size;
  const float* inp  = (const float*)d_in[0];
  const float* U    = (const float*)d_in[1];
  const float* V    = (const float*)d_in[2];
  const float* C    = (const float*)d_in[3];
  const float* gw   = (const float*)d_in[4];
  const float* bias = (const float*)d_in[5];
  float* out = (float*)d_out;

  char* ws = (char*)d_ws;
  size_t o = 0;
  unsigned short* xb  = (unsigned short*)(ws + o); o += (size_t)Bb * Dd * 2;        // 33.55 MB (bf16 state)
  float*          vxp = (float*)(ws + o);          o += (size_t)4 * Bb * 256 * 4;   // 33.55 MB
  unsigned short* wb  = (unsigned short*)(ws + o); o += (size_t)Bb * 256 * 2;       //  4.19 MB
  float*          gsb = (float*)(ws + o);          o += (size_t)Bb * 4 * 4;         //  0.13 MB
  unsigned short* vft = (unsigned short*)(ws + o); o += (size_t)Ll * 256 * Dd * 2;  //  3.15 MB
  unsigned short* uft = (unsigned short*)(ws + o); o += (size_t)Ll * Dd * 256 * 2;  //  3.15 MB
  unsigned short* cb16= (unsigned short*)(ws + o); o += (size_t)Ll * Ee * Rr * Rr * 2; // 0.10 MB
  unsigned short* g16 = (unsigned short*)(ws + o); o += (size_t)Ee * Dd * 2;        //  0.02 MB
  if (ws_size < o) return;

  prep_w_k<<<1024, 256, 0, stream>>>(U, V, C, gw, vft, uft, cb16, g16);

  for (int l = 0; l < Ll; l++){
    if (l == 0){
      gate_k<true><<<Bb / 16, 256, 0, stream>>>(inp, g16, gsb);
      gemm1_k<true><<<dim3(Bb / 64, 2, 4), 256, 0, stream>>>(inp, vft + (size_t)l * 256 * Dd, vxp);
    } else {
      gate_k<false><<<Bb / 16, 256, 0, stream>>>(xb, g16, gsb);
      gemm1_k<false><<<dim3(Bb / 64, 2, 4), 256, 0, stream>>>(xb, vft + (size_t)l * 256 * Dd, vxp);
    }
    gemm2_k<<<dim3(Bb / 64, Ee), 256, 0, stream>>>(vxp, cb16 + (size_t)l * Ee * Rr * Rr, gsb, wb);
    const unsigned short* uftl = uft + (size_t)l * Dd * 256;
    if (l == 0)
      gemm3_k<0><<<dim3(Bb / 64, Dd / 128), 256, 0, stream>>>(wb, uftl, inp, xb, bias + (size_t)l * Dd, out);
    else if (l == 1)
      gemm3_k<1><<<dim3(Bb / 64, Dd / 128), 256, 0, stream>>>(wb, uftl, inp, xb, bias + (size_t)l * Dd, out);
    else
      gemm3_k<2><<<dim3(Bb / 64, Dd / 128), 256, 0, stream>>>(wb, uftl, inp, xb, bias + (size_t)l * Dd, out);
  }
}

// Round 5
// 248.218 us; speedup vs baseline: 1.6146x; 1.1047x over previous
//
#include <hip/hip_runtime.h>
#include <cmath>

#define Bb 8192
#define Dd 2048
#define Rr 64
#define Ee 4
#define Ll 3

typedef __bf16 bf16x8 __attribute__((ext_vector_type(8)));
typedef float f32x4 __attribute__((ext_vector_type(4)));
typedef unsigned short u16x8 __attribute__((ext_vector_type(8)));
typedef unsigned short u16x4 __attribute__((ext_vector_type(4)));

__device__ __forceinline__ unsigned short f2bf(float f){
  unsigned u = __builtin_bit_cast(unsigned, f);
  u += 0x7fffu + ((u >> 16) & 1u);
  return (unsigned short)(u >> 16);
}
__device__ __forceinline__ float bf2f(unsigned short h){
  return __builtin_bit_cast(float, ((unsigned)h) << 16);
}

// ---------------- prep: transpose/cast weights ----------------
__global__ __launch_bounds__(256) void prep_w_k(const float* __restrict__ U,
                                                const float* __restrict__ V,
                                                const float* __restrict__ C,
                                                const float* __restrict__ gw,
                                                unsigned short* __restrict__ VfT,
                                                unsigned short* __restrict__ UfT,
                                                unsigned short* __restrict__ cb16,
                                                unsigned short* __restrict__ gw16){
  const int NV = Ll * 256 * Dd;
  const int NU = Ll * Dd * 256;
  const int NC = Ll * Ee * Rr * Rr;
  const int NG = Ee * Dd;
  const int total = NV + NU + NC + NG;
  for (int idx = blockIdx.x * blockDim.x + threadIdx.x; idx < total; idx += gridDim.x * blockDim.x){
    if (idx < NV){
      int l = idx / (256 * Dd); int rem = idx - l * 256 * Dd;
      int n = rem / Dd, d = rem - n * Dd;
      int e = n >> 6, r = n & 63;
      VfT[idx] = f2bf(V[(((size_t)l * Ee + e) * Dd + d) * Rr + r]);
    } else if (idx < NV + NU){
      int j = idx - NV;
      int l = j / (Dd * 256); int rem = j - l * Dd * 256;
      int d = rem / 256, k = rem - d * 256;
      int e = k >> 6, s = k & 63;
      UfT[j] = f2bf(U[(((size_t)l * Ee + e) * Dd + d) * Rr + s]);
    } else if (idx < NV + NU + NC){
      int j = idx - NV - NU;
      cb16[j] = f2bf(C[j]);
    } else {
      int j = idx - NV - NU - NC;
      gw16[j] = f2bf(gw[j]);
    }
  }
}

// ---------------- gate: one wave per row, fully coalesced ----------------
template<bool AF32>
__global__ __launch_bounds__(256) void gate_k(const void* __restrict__ xv,
                                              const unsigned short* __restrict__ gw16,
                                              float* __restrict__ gs){
  const int lane = threadIdx.x & 63;
  const int w = threadIdx.x >> 6;
  const int row = blockIdx.x * 4 + w;
  float s0 = 0.f, s1 = 0.f, s2 = 0.f, s3 = 0.f;
  #pragma unroll
  for (int c = 0; c < 4; c++){
    const int k = c * 512 + lane * 8;
    float xf[8];
    if constexpr (AF32){
      const float* xr = (const float*)xv + (size_t)row * Dd + k;
      f32x4 v0 = *(const f32x4*)xr;
      f32x4 v1 = *(const f32x4*)(xr + 4);
      #pragma unroll
      for (int u = 0; u < 4; u++){ xf[u] = v0[u]; xf[4 + u] = v1[u]; }
    } else {
      u16x8 xvv = *(const u16x8*)((const unsigned short*)xv + (size_t)row * Dd + k);
      #pragma unroll
      for (int u = 0; u < 8; u++) xf[u] = bf2f(xvv[u]);
    }
    u16x8 g0v = *(const u16x8*)(gw16 + 0 * Dd + k);
    u16x8 g1v = *(const u16x8*)(gw16 + 1 * Dd + k);
    u16x8 g2v = *(const u16x8*)(gw16 + 2 * Dd + k);
    u16x8 g3v = *(const u16x8*)(gw16 + 3 * Dd + k);
    #pragma unroll
    for (int u = 0; u < 8; u++){
      s0 += xf[u] * bf2f(g0v[u]);
      s1 += xf[u] * bf2f(g1v[u]);
      s2 += xf[u] * bf2f(g2v[u]);
      s3 += xf[u] * bf2f(g3v[u]);
    }
  }
  #pragma unroll
  for (int m = 1; m < 64; m <<= 1){
    s0 += __shfl_xor(s0, m, 64);
    s1 += __shfl_xor(s1, m, 64);
    s2 += __shfl_xor(s2, m, 64);
    s3 += __shfl_xor(s3, m, 64);
  }
  if (lane == 0){
    float mx = fmaxf(fmaxf(s0, s1), fmaxf(s2, s3));
    float e0 = __expf(s0 - mx), e1 = __expf(s1 - mx), e2 = __expf(s2 - mx), e3 = __expf(s3 - mx);
    float inv = 1.f / (e0 + e1 + e2 + e3);
    f32x4 g; g[0] = e0 * inv; g[1] = e1 * inv; g[2] = e2 * inv; g[3] = e3 * inv;
    *(f32x4*)(gs + (size_t)row * 4) = g;
  }
}

// ============ G1: T = X @ VfT, split-K=4, separate fp32 partials, BK=64 ============
template<bool AF32>
__global__ __launch_bounds__(256) void gemm1_k(const void* __restrict__ Av,
                                               const unsigned short* __restrict__ BT,
                                               float* __restrict__ vxp){
  const int bm0 = blockIdx.x * 64;
  const int bn0 = blockIdx.y * 128;
  const int z   = blockIdx.z;
  const int kc0 = z * 512;
  const int tid = threadIdx.x;
  const int lane = tid & 63;
  const int wv = tid >> 6;
  const int wm = wv >> 1, wn = wv & 1;

  __shared__ __align__(16) char smraw[27648];
  unsigned short (*As)[72] = (unsigned short (*)[72])smraw;            // 9216 B
  unsigned short (*Bs)[72] = (unsigned short (*)[72])(smraw + 9216);   // 18432 B
  float (*epi)[132] = (float (*)[132])smraw;                           // 16896 B (half-tile)

  f32x4 acc[2][4] = {};
  const int arow = tid >> 2;
  const int aseg = tid & 3;

  const float* Af = (const float*)Av;
  const unsigned short* Ab = (const unsigned short*)Av;

  f32x4 a4[4]; u16x8 ar[2]; u16x8 br[4];
  if constexpr (AF32){
    #pragma unroll
    for (int j = 0; j < 4; j++)
      a4[j] = *(const f32x4*)(Af + (size_t)(bm0 + arow) * Dd + kc0 + aseg * 16 + j * 4);
  } else {
    ar[0] = *(const u16x8*)(Ab + (size_t)(bm0 + arow) * Dd + kc0 + aseg * 16);
    ar[1] = *(const u16x8*)(Ab + (size_t)(bm0 + arow) * Dd + kc0 + aseg * 16 + 8);
  }
  br[0] = *(const u16x8*)(BT + (size_t)(bn0 + arow) * Dd + kc0 + aseg * 16);
  br[1] = *(const u16x8*)(BT + (size_t)(bn0 + arow) * Dd + kc0 + aseg * 16 + 8);
  br[2] = *(const u16x8*)(BT + (size_t)(bn0 + arow + 64) * Dd + kc0 + aseg * 16);
  br[3] = *(const u16x8*)(BT + (size_t)(bn0 + arow + 64) * Dd + kc0 + aseg * 16 + 8);

  for (int k0 = kc0; k0 < kc0 + 512; k0 += 64){
    __syncthreads();
    if constexpr (AF32){
      u16x8 av0, av1;
      #pragma unroll
      for (int j = 0; j < 4; j++){
        av0[j] = f2bf(a4[0][j]); av0[4 + j] = f2bf(a4[1][j]);
        av1[j] = f2bf(a4[2][j]); av1[4 + j] = f2bf(a4[3][j]);
      }
      *(u16x8*)(&As[arow][aseg * 16])     = av0;
      *(u16x8*)(&As[arow][aseg * 16 + 8]) = av1;
    } else {
      *(u16x8*)(&As[arow][aseg * 16])     = ar[0];
      *(u16x8*)(&As[arow][aseg * 16 + 8]) = ar[1];
    }
    *(u16x8*)(&Bs[arow][aseg * 16])          = br[0];
    *(u16x8*)(&Bs[arow][aseg * 16 + 8])      = br[1];
    *(u16x8*)(&Bs[arow + 64][aseg * 16])     = br[2];
    *(u16x8*)(&Bs[arow + 64][aseg * 16 + 8]) = br[3];
    __syncthreads();

    int kn = k0 + 64;
    if (kn < kc0 + 512){
      if constexpr (AF32){
        #pragma unroll
        for (int j = 0; j < 4; j++)
          a4[j] = *(const f32x4*)(Af + (size_t)(bm0 + arow) * Dd + kn + aseg * 16 + j * 4);
      } else {
        ar[0] = *(const u16x8*)(Ab + (size_t)(bm0 + arow) * Dd + kn + aseg * 16);
        ar[1] = *(const u16x8*)(Ab + (size_t)(bm0 + arow) * Dd + kn + aseg * 16 + 8);
      }
      br[0] = *(const u16x8*)(BT + (size_t)(bn0 + arow) * Dd + kn + aseg * 16);
      br[1] = *(const u16x8*)(BT + (size_t)(bn0 + arow) * Dd + kn + aseg * 16 + 8);
      br[2] = *(const u16x8*)(BT + (size_t)(bn0 + arow + 64) * Dd + kn + aseg * 16);
      br[3] = *(const u16x8*)(BT + (size_t)(bn0 + arow + 64) * Dd + kn + aseg * 16 + 8);
    }

    #pragma unroll
    for (int ks = 0; ks < 2; ks++){
      bf16x8 af[2];
      #pragma unroll
      for (int mi = 0; mi < 2; mi++)
        af[mi] = *reinterpret_cast<const bf16x8*>(&As[wm * 32 + mi * 16 + (lane & 15)][ks * 32 + (lane >> 4) * 8]);
      #pragma unroll
      for (int nj = 0; nj < 4; nj++){
        bf16x8 bfr = *reinterpret_cast<const bf16x8*>(&Bs[wn * 64 + nj * 16 + (lane & 15)][ks * 32 + (lane >> 4) * 8]);
        #pragma unroll
        for (int mi = 0; mi < 2; mi++)
          acc[mi][nj] = __builtin_amdgcn_mfma_f32_16x16x32_bf16(af[mi], bfr, acc[mi][nj], 0, 0, 0);
      }
    }
  }

  float* outz = vxp + (size_t)z * Bb * 256;
  #pragma unroll
  for (int h = 0; h < 2; h++){
    __syncthreads();
    if (wm == h){
      #pragma unroll
      for (int mi = 0; mi < 2; mi++)
        #pragma unroll
        for (int nj = 0; nj < 4; nj++)
          #pragma unroll
          for (int q = 0; q < 4; q++)
            epi[mi * 16 + (lane >> 4) * 4 + q][wn * 64 + nj * 16 + (lane & 15)] = acc[mi][nj][q];
    }
    __syncthreads();
    #pragma unroll
    for (int c = 0; c < 4; c++){
      int idx = c * 256 + tid;
      int r = idx >> 5;
      int col = (idx & 31) * 4;
      *(f32x4*)(outz + (size_t)(bm0 + h * 32 + r) * 256 + bn0 + col) = *(const f32x4*)&epi[r][col];
    }
  }
}

// ============ G2: block-diag C. Expert e needs only K in [64e, 64e+64) ============
__global__ __launch_bounds__(256) void gemm2_k(const float* __restrict__ vxp,
                                               const unsigned short* __restrict__ cb,
                                               const float* __restrict__ gs,
                                               unsigned short* __restrict__ wb){
  const int bm0 = blockIdx.x * 64;
  const int e   = blockIdx.y;
  const int tid = threadIdx.x;
  const int lane = tid & 63;
  const int wv = tid >> 6;
  const int wm = wv >> 1, wn = wv & 1;

  __shared__ __align__(16) char smraw[18432];
  unsigned short (*As)[72] = (unsigned short (*)[72])smraw;
  unsigned short (*Bs)[72] = (unsigned short (*)[72])(smraw + 9216);
  unsigned short (*epi)[72] = (unsigned short (*)[72])smraw;

  const int arow = tid >> 2;
  const int aseg = tid & 3;

  f32x4 t[4];
  #pragma unroll
  for (int j = 0; j < 4; j++)
    t[j] = *(const f32x4*)(vxp + (size_t)(bm0 + arow) * 256 + e * 64 + aseg * 16 + j * 4);
  #pragma unroll
  for (int z = 1; z < 4; z++)
    #pragma unroll
    for (int j = 0; j < 4; j++)
      t[j] += *(const f32x4*)(vxp + (size_t)z * Bb * 256 + (size_t)(bm0 + arow) * 256 + e * 64 + aseg * 16 + j * 4);
  u16x8 av0, av1;
  #pragma unroll
  for (int j = 0; j < 4; j++){
    av0[j] = f2bf(tanhf(t[0][j])); av0[4 + j] = f2bf(tanhf(t[1][j]));
    av1[j] = f2bf(tanhf(t[2][j])); av1[4 + j] = f2bf(tanhf(t[3][j]));
  }
  *(u16x8*)(&As[arow][aseg * 16]) = av0;
  *(u16x8*)(&As[arow][aseg * 16 + 8]) = av1;
  *(u16x8*)(&Bs[arow][aseg * 16])     = *(const u16x8*)(cb + e * 4096 + arow * 64 + aseg * 16);
  *(u16x8*)(&Bs[arow][aseg * 16 + 8]) = *(const u16x8*)(cb + e * 4096 + arow * 64 + aseg * 16 + 8);
  __syncthreads();

  f32x4 acc[2][2] = {};
  #pragma unroll
  for (int kk = 0; kk < 2; kk++){
    bf16x8 af[2];
    #pragma unroll
    for (int mi = 0; mi < 2; mi++)
      af[mi] = *reinterpret_cast<const bf16x8*>(&As[wm * 32 + mi * 16 + (lane & 15)][kk * 32 + (lane >> 4) * 8]);
    #pragma unroll
    for (int nj = 0; nj < 2; nj++){
      bf16x8 bfr = *reinterpret_cast<const bf16x8*>(&Bs[wn * 32 + nj * 16 + (lane & 15)][kk * 32 + (lane >> 4) * 8]);
      #pragma unroll
      for (int mi = 0; mi < 2; mi++)
        acc[mi][nj] = __builtin_amdgcn_mfma_f32_16x16x32_bf16(af[mi], bfr, acc[mi][nj], 0, 0, 0);
    }
  }

  __syncthreads();
  #pragma unroll
  for (int mi = 0; mi < 2; mi++)
    #pragma unroll
    for (int nj = 0; nj < 2; nj++)
      #pragma unroll
      for (int q = 0; q < 4; q++){
        int row = wm * 32 + mi * 16 + (lane >> 4) * 4 + q;
        int col = wn * 32 + nj * 16 + (lane & 15);
        float g = gs[(size_t)(bm0 + row) * 4 + e];
        epi[row][col] = f2bf(g * tanhf(acc[mi][nj][q]));
      }
  __syncthreads();
  #pragma unroll
  for (int c = 0; c < 2; c++){
    int idx = c * 256 + tid;
    int row = idx >> 3;
    int col = (idx & 7) * 8;
    *(u16x8*)(wb + (size_t)(bm0 + row) * 256 + e * 64 + col) = *(const u16x8*)(&epi[row][col]);
  }
}

// ============ G3: Y = wb @ UfT; x_new = x_old + x0*(bias + Y), bf16 state ============
// MODE 0: xold = x0 (inp f32), write bf16 state    (layer 0)
// MODE 1: xold = bf16 state, in-place RMW           (layer 1)
// MODE 2: xold = bf16 state, write fp32 out only    (layer 2)
// Epilogue operands (x0, xst) are preloaded BEFORE the K-loop so HBM latency
// hides under the GEMM. __launch_bounds__(256,4) pins VGPR<=128 tier.
template<int MODE>
__global__ __launch_bounds__(256, 4) void gemm3_k(const unsigned short* __restrict__ A,
                                                  const unsigned short* __restrict__ BT,
                                                  const float* __restrict__ x0f,
                                                  unsigned short* __restrict__ xst,
                                                  const float* __restrict__ biasrow,
                                                  float* __restrict__ out){
  const int bm0 = blockIdx.x * 64;
  const int bn0 = blockIdx.y * 128;
  const int tid = threadIdx.x;
  const int lane = tid & 63;
  const int wv = tid >> 6;
  const int wm = wv >> 1, wn = wv & 1;

  __shared__ __align__(16) char smraw[17408];
  unsigned short (*As)[40] = (unsigned short (*)[40])smraw;            // 5120 B
  unsigned short (*Bs)[40] = (unsigned short (*)[40])(smraw + 5120);   // 10240 B
  float (*epi)[132] = (float (*)[132])smraw;                           // 16896 B (half)

  f32x4 acc[2][4] = {};
  const int arow = tid >> 2;
  const int aseg = tid & 3;

  // ---- preload epilogue operands (independent of GEMM) ----
  f32x4 x0p[8];
  u16x4 xsp[8];
  #pragma unroll
  for (int h = 0; h < 2; h++)
    #pragma unroll
    for (int c = 0; c < 4; c++){
      int idx = c * 256 + tid;
      int r = idx >> 5;
      int col = (idx & 31) * 4;
      size_t o = (size_t)(bm0 + h * 32 + r) * Dd + bn0 + col;
      x0p[h * 4 + c] = *(const f32x4*)(x0f + o);
      if constexpr (MODE != 0) xsp[h * 4 + c] = *(const u16x4*)(xst + o);
    }

  u16x8 areg  = *(const u16x8*)(A  + (size_t)(bm0 + arow) * 256 + aseg * 8);
  u16x8 breg0 = *(const u16x8*)(BT + (size_t)(bn0 + arow) * 256 + aseg * 8);
  u16x8 breg1 = *(const u16x8*)(BT + (size_t)(bn0 + arow + 64) * 256 + aseg * 8);

  for (int k0 = 0; k0 < 256; k0 += 32){
    __syncthreads();
    *(u16x8*)(&As[arow][aseg * 8]) = areg;
    *(u16x8*)(&Bs[arow][aseg * 8]) = breg0;
    *(u16x8*)(&Bs[arow + 64][aseg * 8]) = breg1;
    __syncthreads();
    if (k0 + 32 < 256){
      areg  = *(const u16x8*)(A  + (size_t)(bm0 + arow) * 256 + k0 + 32 + aseg * 8);
      breg0 = *(const u16x8*)(BT + (size_t)(bn0 + arow) * 256 + k0 + 32 + aseg * 8);
      breg1 = *(const u16x8*)(BT + (size_t)(bn0 + arow + 64) * 256 + k0 + 32 + aseg * 8);
    }
    bf16x8 af[2];
    #pragma unroll
    for (int mi = 0; mi < 2; mi++)
      af[mi] = *reinterpret_cast<const bf16x8*>(&As[wm * 32 + mi * 16 + (lane & 15)][(lane >> 4) * 8]);
    #pragma unroll
    for (int nj = 0; nj < 4; nj++){
      bf16x8 bfr = *reinterpret_cast<const bf16x8*>(&Bs[wn * 64 + nj * 16 + (lane & 15)][(lane >> 4) * 8]);
      #pragma unroll
      for (int mi = 0; mi < 2; mi++)
        acc[mi][nj] = __builtin_amdgcn_mfma_f32_16x16x32_bf16(af[mi], bfr, acc[mi][nj], 0, 0, 0);
    }
  }

  #pragma unroll
  for (int h = 0; h < 2; h++){
    __syncthreads();
    if (wm == h){
      #pragma unroll
      for (int mi = 0; mi < 2; mi++)
        #pragma unroll
        for (int nj = 0; nj < 4; nj++)
          #pragma unroll
          for (int q = 0; q < 4; q++)
            epi[mi * 16 + (lane >> 4) * 4 + q][wn * 64 + nj * 16 + (lane & 15)] = acc[mi][nj][q];
    }
    __syncthreads();
    #pragma unroll
    for (int c = 0; c < 4; c++){
      int idx = c * 256 + tid;
      int r = idx >> 5;
      int col = (idx & 31) * 4;
      int row = bm0 + h * 32 + r;
      size_t o = (size_t)row * Dd + bn0 + col;
      f32x4 y = *(const f32x4*)&epi[r][col];
      f32x4 x0v = x0p[h * 4 + c];
      f32x4 bv  = *(const f32x4*)(biasrow + bn0 + col);
      f32x4 xo;
      if constexpr (MODE == 0){
        xo = x0v;
      } else {
        u16x4 xv = xsp[h * 4 + c];
        #pragma unroll
        for (int j = 0; j < 4; j++) xo[j] = bf2f(xv[j]);
      }
      f32x4 xn;
      #pragma unroll
      for (int j = 0; j < 4; j++) xn[j] = xo[j] + x0v[j] * (bv[j] + y[j]);
      if constexpr (MODE == 2){
        *(f32x4*)(out + o) = xn;
      } else {
        u16x4 xnb;
        #pragma unroll
        for (int j = 0; j < 4; j++) xnb[j] = f2bf(xn[j]);
        *(u16x4*)(xst + o) = xnb;
      }
    }
  }
}

extern "C" void kernel_launch(void* const* d_in, const int* in_sizes, int n_in,
                              void* d_out, int out_size, void* d_ws, size_t ws_size,
                              hipStream_t stream){
  (void)in_sizes; (void)n_in; (void)out_size;
  const float* inp  = (const float*)d_in[0];
  const float* U    = (const float*)d_in[1];
  const float* V    = (const float*)d_in[2];
  const float* C    = (const float*)d_in[3];
  const float* gw   = (const float*)d_in[4];
  const float* bias = (const float*)d_in[5];
  float* out = (float*)d_out;

  char* ws = (char*)d_ws;
  size_t o = 0;
  unsigned short* xb  = (unsigned short*)(ws + o); o += (size_t)Bb * Dd * 2;        // 33.55 MB (bf16 state)
  float*          vxp = (float*)(ws + o);          o += (size_t)4 * Bb * 256 * 4;   // 33.55 MB
  unsigned short* wb  = (unsigned short*)(ws + o); o += (size_t)Bb * 256 * 2;       //  4.19 MB
  float*          gsb = (float*)(ws + o);          o += (size_t)Bb * 4 * 4;         //  0.13 MB
  unsigned short* vft = (unsigned short*)(ws + o); o += (size_t)Ll * 256 * Dd * 2;  //  3.15 MB
  unsigned short* uft = (unsigned short*)(ws + o); o += (size_t)Ll * Dd * 256 * 2;  //  3.15 MB
  unsigned short* cb16= (unsigned short*)(ws + o); o += (size_t)Ll * Ee * Rr * Rr * 2; // 0.10 MB
  unsigned short* g16 = (unsigned short*)(ws + o); o += (size_t)Ee * Dd * 2;        //  0.02 MB
  if (ws_size < o) return;

  prep_w_k<<<1024, 256, 0, stream>>>(U, V, C, gw, vft, uft, cb16, g16);

  for (int l = 0; l < Ll; l++){
    if (l == 0){
      gate_k<true><<<Bb / 4, 256, 0, stream>>>(inp, g16, gsb);
      gemm1_k<true><<<dim3(Bb / 64, 2, 4), 256, 0, stream>>>(inp, vft + (size_t)l * 256 * Dd, vxp);
    } else {
      gate_k<false><<<Bb / 4, 256, 0, stream>>>(xb, g16, gsb);
      gemm1_k<false><<<dim3(Bb / 64, 2, 4), 256, 0, stream>>>(xb, vft + (size_t)l * 256 * Dd, vxp);
    }
    gemm2_k<<<dim3(Bb / 64, Ee), 256, 0, stream>>>(vxp, cb16 + (size_t)l * Ee * Rr * Rr, gsb, wb);
    const unsigned short* uftl = uft + (size_t)l * Dd * 256;
    if (l == 0)
      gemm3_k<0><<<dim3(Bb / 64, Dd / 128), 256, 0, stream>>>(wb, uftl, inp, xb, bias + (size_t)l * Dd, out);
    else if (l == 1)
      gemm3_k<1><<<dim3(Bb / 64, Dd / 128), 256, 0, stream>>>(wb, uftl, inp, xb, bias + (size_t)l * Dd, out);
    else
      gemm3_k<2><<<dim3(Bb / 64, Dd / 128), 256, 0, stream>>>(wb, uftl, inp, xb, bias + (size_t)l * Dd, out);
  }
}

// Round 6
// 218.038 us; speedup vs baseline: 1.8380x; 1.1384x over previous
//
#include <hip/hip_runtime.h>
#include <cmath>

#define Bb 8192
#define Dd 2048
#define Rr 64
#define Ee 4
#define Ll 3

typedef __bf16 bf16x8 __attribute__((ext_vector_type(8)));
typedef float f32x4 __attribute__((ext_vector_type(4)));
typedef unsigned short u16x8 __attribute__((ext_vector_type(8)));
typedef unsigned short u16x4 __attribute__((ext_vector_type(4)));

__device__ __forceinline__ unsigned short f2bf(float f){
  unsigned u = __builtin_bit_cast(unsigned, f);
  u += 0x7fffu + ((u >> 16) & 1u);
  return (unsigned short)(u >> 16);
}
__device__ __forceinline__ float bf2f(unsigned short h){
  return __builtin_bit_cast(float, ((unsigned)h) << 16);
}

// ---------------- cast: x0b = bf16(inp) ----------------
__global__ __launch_bounds__(256) void cast_x_k(const float* __restrict__ x,
                                                unsigned short* __restrict__ xb0){
  const int n4 = Bb * Dd / 4;
  for (int i = blockIdx.x * blockDim.x + threadIdx.x; i < n4; i += gridDim.x * blockDim.x){
    f32x4 v = *((const f32x4*)x + i);
    u16x4 o;
    o[0] = f2bf(v[0]); o[1] = f2bf(v[1]); o[2] = f2bf(v[2]); o[3] = f2bf(v[3]);
    *((u16x4*)xb0 + i) = o;
  }
}

// ---------------- prep: transpose/cast weights ----------------
__global__ __launch_bounds__(256) void prep_w_k(const float* __restrict__ U,
                                                const float* __restrict__ V,
                                                const float* __restrict__ C,
                                                const float* __restrict__ gw,
                                                unsigned short* __restrict__ VfT,
                                                unsigned short* __restrict__ UfT,
                                                unsigned short* __restrict__ cb16,
                                                unsigned short* __restrict__ gw16){
  const int NV = Ll * 256 * Dd;
  const int NU = Ll * Dd * 256;
  const int NC = Ll * Ee * Rr * Rr;
  const int NG = Ee * Dd;
  const int total = NV + NU + NC + NG;
  for (int idx = blockIdx.x * blockDim.x + threadIdx.x; idx < total; idx += gridDim.x * blockDim.x){
    if (idx < NV){
      int l = idx / (256 * Dd); int rem = idx - l * 256 * Dd;
      int n = rem / Dd, d = rem - n * Dd;
      int e = n >> 6, r = n & 63;
      VfT[idx] = f2bf(V[(((size_t)l * Ee + e) * Dd + d) * Rr + r]);
    } else if (idx < NV + NU){
      int j = idx - NV;
      int l = j / (Dd * 256); int rem = j - l * Dd * 256;
      int d = rem / 256, k = rem - d * 256;
      int e = k >> 6, s = k & 63;
      UfT[j] = f2bf(U[(((size_t)l * Ee + e) * Dd + d) * Rr + s]);
    } else if (idx < NV + NU + NC){
      int j = idx - NV - NU;
      cb16[j] = f2bf(C[j]);
    } else {
      int j = idx - NV - NU - NC;
      gw16[j] = f2bf(gw[j]);
    }
  }
}

// ---------------- gate (layer 0 only): one wave per row, coalesced ----------------
template<bool AF32>
__global__ __launch_bounds__(256) void gate_k(const void* __restrict__ xv,
                                              const unsigned short* __restrict__ gw16,
                                              float* __restrict__ gs){
  const int lane = threadIdx.x & 63;
  const int w = threadIdx.x >> 6;
  const int row = blockIdx.x * 4 + w;
  float s0 = 0.f, s1 = 0.f, s2 = 0.f, s3 = 0.f;
  #pragma unroll
  for (int c = 0; c < 4; c++){
    const int k = c * 512 + lane * 8;
    float xf[8];
    if constexpr (AF32){
      const float* xr = (const float*)xv + (size_t)row * Dd + k;
      f32x4 v0 = *(const f32x4*)xr;
      f32x4 v1 = *(const f32x4*)(xr + 4);
      #pragma unroll
      for (int u = 0; u < 4; u++){ xf[u] = v0[u]; xf[4 + u] = v1[u]; }
    } else {
      u16x8 xvv = *(const u16x8*)((const unsigned short*)xv + (size_t)row * Dd + k);
      #pragma unroll
      for (int u = 0; u < 8; u++) xf[u] = bf2f(xvv[u]);
    }
    u16x8 g0v = *(const u16x8*)(gw16 + 0 * Dd + k);
    u16x8 g1v = *(const u16x8*)(gw16 + 1 * Dd + k);
    u16x8 g2v = *(const u16x8*)(gw16 + 2 * Dd + k);
    u16x8 g3v = *(const u16x8*)(gw16 + 3 * Dd + k);
    #pragma unroll
    for (int u = 0; u < 8; u++){
      s0 += xf[u] * bf2f(g0v[u]);
      s1 += xf[u] * bf2f(g1v[u]);
      s2 += xf[u] * bf2f(g2v[u]);
      s3 += xf[u] * bf2f(g3v[u]);
    }
  }
  #pragma unroll
  for (int m = 1; m < 64; m <<= 1){
    s0 += __shfl_xor(s0, m, 64);
    s1 += __shfl_xor(s1, m, 64);
    s2 += __shfl_xor(s2, m, 64);
    s3 += __shfl_xor(s3, m, 64);
  }
  if (lane == 0){
    float mx = fmaxf(fmaxf(s0, s1), fmaxf(s2, s3));
    float e0 = __expf(s0 - mx), e1 = __expf(s1 - mx), e2 = __expf(s2 - mx), e3 = __expf(s3 - mx);
    float inv = 1.f / (e0 + e1 + e2 + e3);
    f32x4 g; g[0] = e0 * inv; g[1] = e1 * inv; g[2] = e2 * inv; g[3] = e3 * inv;
    *(f32x4*)(gs + (size_t)row * 4) = g;
  }
}

// ============ G1: T = X @ VfT, split-K=4, bf16 partials, BK=64 ============
template<bool AF32>
__global__ __launch_bounds__(256) void gemm1_k(const void* __restrict__ Av,
                                               const unsigned short* __restrict__ BT,
                                               unsigned short* __restrict__ vxp){
  const int bm0 = blockIdx.x * 64;
  const int bn0 = blockIdx.y * 128;
  const int z   = blockIdx.z;
  const int kc0 = z * 512;
  const int tid = threadIdx.x;
  const int lane = tid & 63;
  const int wv = tid >> 6;
  const int wm = wv >> 1, wn = wv & 1;

  __shared__ __align__(16) char smraw[27648];
  unsigned short (*As)[72] = (unsigned short (*)[72])smraw;            // 9216 B
  unsigned short (*Bs)[72] = (unsigned short (*)[72])(smraw + 9216);   // 18432 B
  float (*epi)[132] = (float (*)[132])smraw;                           // 16896 B (half-tile)

  f32x4 acc[2][4] = {};
  const int arow = tid >> 2;
  const int aseg = tid & 3;

  const float* Af = (const float*)Av;
  const unsigned short* Ab = (const unsigned short*)Av;

  f32x4 a4[4]; u16x8 ar[2]; u16x8 br[4];
  if constexpr (AF32){
    #pragma unroll
    for (int j = 0; j < 4; j++)
      a4[j] = *(const f32x4*)(Af + (size_t)(bm0 + arow) * Dd + kc0 + aseg * 16 + j * 4);
  } else {
    ar[0] = *(const u16x8*)(Ab + (size_t)(bm0 + arow) * Dd + kc0 + aseg * 16);
    ar[1] = *(const u16x8*)(Ab + (size_t)(bm0 + arow) * Dd + kc0 + aseg * 16 + 8);
  }
  br[0] = *(const u16x8*)(BT + (size_t)(bn0 + arow) * Dd + kc0 + aseg * 16);
  br[1] = *(const u16x8*)(BT + (size_t)(bn0 + arow) * Dd + kc0 + aseg * 16 + 8);
  br[2] = *(const u16x8*)(BT + (size_t)(bn0 + arow + 64) * Dd + kc0 + aseg * 16);
  br[3] = *(const u16x8*)(BT + (size_t)(bn0 + arow + 64) * Dd + kc0 + aseg * 16 + 8);

  for (int k0 = kc0; k0 < kc0 + 512; k0 += 64){
    __syncthreads();
    if constexpr (AF32){
      u16x8 av0, av1;
      #pragma unroll
      for (int j = 0; j < 4; j++){
        av0[j] = f2bf(a4[0][j]); av0[4 + j] = f2bf(a4[1][j]);
        av1[j] = f2bf(a4[2][j]); av1[4 + j] = f2bf(a4[3][j]);
      }
      *(u16x8*)(&As[arow][aseg * 16])     = av0;
      *(u16x8*)(&As[arow][aseg * 16 + 8]) = av1;
    } else {
      *(u16x8*)(&As[arow][aseg * 16])     = ar[0];
      *(u16x8*)(&As[arow][aseg * 16 + 8]) = ar[1];
    }
    *(u16x8*)(&Bs[arow][aseg * 16])          = br[0];
    *(u16x8*)(&Bs[arow][aseg * 16 + 8])      = br[1];
    *(u16x8*)(&Bs[arow + 64][aseg * 16])     = br[2];
    *(u16x8*)(&Bs[arow + 64][aseg * 16 + 8]) = br[3];
    __syncthreads();

    int kn = k0 + 64;
    if (kn < kc0 + 512){
      if constexpr (AF32){
        #pragma unroll
        for (int j = 0; j < 4; j++)
          a4[j] = *(const f32x4*)(Af + (size_t)(bm0 + arow) * Dd + kn + aseg * 16 + j * 4);
      } else {
        ar[0] = *(const u16x8*)(Ab + (size_t)(bm0 + arow) * Dd + kn + aseg * 16);
        ar[1] = *(const u16x8*)(Ab + (size_t)(bm0 + arow) * Dd + kn + aseg * 16 + 8);
      }
      br[0] = *(const u16x8*)(BT + (size_t)(bn0 + arow) * Dd + kn + aseg * 16);
      br[1] = *(const u16x8*)(BT + (size_t)(bn0 + arow) * Dd + kn + aseg * 16 + 8);
      br[2] = *(const u16x8*)(BT + (size_t)(bn0 + arow + 64) * Dd + kn + aseg * 16);
      br[3] = *(const u16x8*)(BT + (size_t)(bn0 + arow + 64) * Dd + kn + aseg * 16 + 8);
    }

    #pragma unroll
    for (int ks = 0; ks < 2; ks++){
      bf16x8 af[2];
      #pragma unroll
      for (int mi = 0; mi < 2; mi++)
        af[mi] = *reinterpret_cast<const bf16x8*>(&As[wm * 32 + mi * 16 + (lane & 15)][ks * 32 + (lane >> 4) * 8]);
      #pragma unroll
      for (int nj = 0; nj < 4; nj++){
        bf16x8 bfr = *reinterpret_cast<const bf16x8*>(&Bs[wn * 64 + nj * 16 + (lane & 15)][ks * 32 + (lane >> 4) * 8]);
        #pragma unroll
        for (int mi = 0; mi < 2; mi++)
          acc[mi][nj] = __builtin_amdgcn_mfma_f32_16x16x32_bf16(af[mi], bfr, acc[mi][nj], 0, 0, 0);
      }
    }
  }

  unsigned short* outz = vxp + (size_t)z * Bb * 256;
  #pragma unroll
  for (int h = 0; h < 2; h++){
    __syncthreads();
    if (wm == h){
      #pragma unroll
      for (int mi = 0; mi < 2; mi++)
        #pragma unroll
        for (int nj = 0; nj < 4; nj++)
          #pragma unroll
          for (int q = 0; q < 4; q++)
            epi[mi * 16 + (lane >> 4) * 4 + q][wn * 64 + nj * 16 + (lane & 15)] = acc[mi][nj][q];
    }
    __syncthreads();
    #pragma unroll
    for (int c = 0; c < 4; c++){
      int idx = c * 256 + tid;
      int r = idx >> 5;
      int col = (idx & 31) * 4;
      f32x4 v = *(const f32x4*)&epi[r][col];
      u16x4 ov;
      #pragma unroll
      for (int j = 0; j < 4; j++) ov[j] = f2bf(v[j]);
      *(u16x4*)(outz + (size_t)(bm0 + h * 32 + r) * 256 + bn0 + col) = ov;
    }
  }
}

// ============ G2: block-diag C; sums bf16 partials; softmax from plog (l>=1) ============
template<bool FROMPLOG>
__global__ __launch_bounds__(256) void gemm2_k(const unsigned short* __restrict__ vxp,
                                               const unsigned short* __restrict__ cb,
                                               const float* __restrict__ gsb,
                                               const float* __restrict__ plog,
                                               unsigned short* __restrict__ wb){
  const int bm0 = blockIdx.x * 64;
  const int e   = blockIdx.y;
  const int tid = threadIdx.x;
  const int lane = tid & 63;
  const int wv = tid >> 6;
  const int wm = wv >> 1, wn = wv & 1;

  __shared__ __align__(16) char smraw[19456];
  unsigned short (*As)[72] = (unsigned short (*)[72])smraw;            // 9216
  unsigned short (*Bs)[72] = (unsigned short (*)[72])(smraw + 9216);   // 9216
  float (*gs_l)[4] = (float (*)[4])(smraw + 18432);                    // 1024
  unsigned short (*epi)[72] = (unsigned short (*)[72])smraw;           // union As

  // ---- gate weights for the block's 64 rows ----
  if constexpr (FROMPLOG){
    int r = tid >> 2, q = tid & 3;
    f32x4 s = {0.f, 0.f, 0.f, 0.f};
    #pragma unroll
    for (int ci = 0; ci < 4; ci++)
      s += *(const f32x4*)(plog + ((size_t)(q * 4 + ci) * Bb + bm0 + r) * 4);
    #pragma unroll
    for (int j = 0; j < 4; j++){
      s[j] += __shfl_xor(s[j], 1, 64);
      s[j] += __shfl_xor(s[j], 2, 64);
    }
    if (q == 0){
      float mx = fmaxf(fmaxf(s[0], s[1]), fmaxf(s[2], s[3]));
      float e0 = __expf(s[0] - mx), e1 = __expf(s[1] - mx), e2 = __expf(s[2] - mx), e3 = __expf(s[3] - mx);
      float inv = 1.f / (e0 + e1 + e2 + e3);
      f32x4 g; g[0] = e0 * inv; g[1] = e1 * inv; g[2] = e2 * inv; g[3] = e3 * inv;
      *(f32x4*)&gs_l[r][0] = g;
    }
  } else {
    if (tid < 64) *(f32x4*)&gs_l[tid][0] = *(const f32x4*)(gsb + (size_t)(bm0 + tid) * 4);
  }

  const int arow = tid >> 2;
  const int aseg = tid & 3;

  // A: sum 4 bf16 partials + tanh -> bf16 LDS
  float tv[16];
  #pragma unroll
  for (int j = 0; j < 16; j++) tv[j] = 0.f;
  #pragma unroll
  for (int z = 0; z < 4; z++){
    const unsigned short* vz = vxp + ((size_t)z * Bb + bm0 + arow) * 256 + e * 64 + aseg * 16;
    u16x8 p0 = *(const u16x8*)vz;
    u16x8 p1 = *(const u16x8*)(vz + 8);
    #pragma unroll
    for (int j = 0; j < 8; j++){ tv[j] += bf2f(p0[j]); tv[8 + j] += bf2f(p1[j]); }
  }
  u16x8 av0, av1;
  #pragma unroll
  for (int j = 0; j < 4; j++){
    av0[j] = f2bf(tanhf(tv[j]));     av0[4 + j] = f2bf(tanhf(tv[4 + j]));
    av1[j] = f2bf(tanhf(tv[8 + j])); av1[4 + j] = f2bf(tanhf(tv[12 + j]));
  }
  *(u16x8*)(&As[arow][aseg * 16]) = av0;
  *(u16x8*)(&As[arow][aseg * 16 + 8]) = av1;
  *(u16x8*)(&Bs[arow][aseg * 16])     = *(const u16x8*)(cb + e * 4096 + arow * 64 + aseg * 16);
  *(u16x8*)(&Bs[arow][aseg * 16 + 8]) = *(const u16x8*)(cb + e * 4096 + arow * 64 + aseg * 16 + 8);
  __syncthreads();

  f32x4 acc[2][2] = {};
  #pragma unroll
  for (int kk = 0; kk < 2; kk++){
    bf16x8 af[2];
    #pragma unroll
    for (int mi = 0; mi < 2; mi++)
      af[mi] = *reinterpret_cast<const bf16x8*>(&As[wm * 32 + mi * 16 + (lane & 15)][kk * 32 + (lane >> 4) * 8]);
    #pragma unroll
    for (int nj = 0; nj < 2; nj++){
      bf16x8 bfr = *reinterpret_cast<const bf16x8*>(&Bs[wn * 32 + nj * 16 + (lane & 15)][kk * 32 + (lane >> 4) * 8]);
      #pragma unroll
      for (int mi = 0; mi < 2; mi++)
        acc[mi][nj] = __builtin_amdgcn_mfma_f32_16x16x32_bf16(af[mi], bfr, acc[mi][nj], 0, 0, 0);
    }
  }

  __syncthreads();
  #pragma unroll
  for (int mi = 0; mi < 2; mi++)
    #pragma unroll
    for (int nj = 0; nj < 2; nj++)
      #pragma unroll
      for (int q = 0; q < 4; q++){
        int row = wm * 32 + mi * 16 + (lane >> 4) * 4 + q;
        int col = wn * 32 + nj * 16 + (lane & 15);
        float g = gs_l[row][e];
        epi[row][col] = f2bf(g * tanhf(acc[mi][nj][q]));
      }
  __syncthreads();
  #pragma unroll
  for (int c = 0; c < 2; c++){
    int idx = c * 256 + tid;
    int row = idx >> 3;
    int col = (idx & 7) * 8;
    *(u16x8*)(wb + (size_t)(bm0 + row) * 256 + e * 64 + col) = *(const u16x8*)(&epi[row][col]);
  }
}

// ============ G3: Y = wb @ UfT; x_new = xold + x0*(bias + Y); fused next-gate ============
// MODE 0: xold = x0, write bf16 state + plog       (layer 0)
// MODE 1: xold = bf16 state RMW, + plog            (layer 1)
// MODE 2: xold = bf16 state, write fp32 out        (layer 2, no plog)
// X0BF: x0 read as bf16 (x0b) vs fp32 (inp)
template<int MODE, bool X0BF>
__global__ __launch_bounds__(256, 4) void gemm3_k(const unsigned short* __restrict__ A,
                                                  const unsigned short* __restrict__ BT,
                                                  const float* __restrict__ x0f,
                                                  const unsigned short* __restrict__ x0b,
                                                  unsigned short* __restrict__ xst,
                                                  const float* __restrict__ biasrow,
                                                  float* __restrict__ out,
                                                  const unsigned short* __restrict__ gw16,
                                                  float* __restrict__ plog){
  const int bm0 = blockIdx.x * 64;
  const int bn0 = blockIdx.y * 128;
  const int tid = threadIdx.x;
  const int lane = tid & 63;
  const int wv = tid >> 6;
  const int wm = wv >> 1, wn = wv & 1;

  __shared__ __align__(16) char smraw[17408];
  unsigned short (*As)[40] = (unsigned short (*)[40])smraw;            // 5120 B
  unsigned short (*Bs)[40] = (unsigned short (*)[40])(smraw + 5120);   // 10240 B
  float (*epi)[132] = (float (*)[132])smraw;                           // 16896 B (half)

  f32x4 acc[2][4] = {};
  const int arow = tid >> 2;
  const int aseg = tid & 3;

  u16x8 areg  = *(const u16x8*)(A  + (size_t)(bm0 + arow) * 256 + aseg * 8);
  u16x8 breg0 = *(const u16x8*)(BT + (size_t)(bn0 + arow) * 256 + aseg * 8);
  u16x8 breg1 = *(const u16x8*)(BT + (size_t)(bn0 + arow + 64) * 256 + aseg * 8);

  for (int k0 = 0; k0 < 256; k0 += 32){
    __syncthreads();
    *(u16x8*)(&As[arow][aseg * 8]) = areg;
    *(u16x8*)(&Bs[arow][aseg * 8]) = breg0;
    *(u16x8*)(&Bs[arow + 64][aseg * 8]) = breg1;
    __syncthreads();
    if (k0 + 32 < 256){
      areg  = *(const u16x8*)(A  + (size_t)(bm0 + arow) * 256 + k0 + 32 + aseg * 8);
      breg0 = *(const u16x8*)(BT + (size_t)(bn0 + arow) * 256 + k0 + 32 + aseg * 8);
      breg1 = *(const u16x8*)(BT + (size_t)(bn0 + arow + 64) * 256 + k0 + 32 + aseg * 8);
    }
    bf16x8 af[2];
    #pragma unroll
    for (int mi = 0; mi < 2; mi++)
      af[mi] = *reinterpret_cast<const bf16x8*>(&As[wm * 32 + mi * 16 + (lane & 15)][(lane >> 4) * 8]);
    #pragma unroll
    for (int nj = 0; nj < 4; nj++){
      bf16x8 bfr = *reinterpret_cast<const bf16x8*>(&Bs[wn * 64 + nj * 16 + (lane & 15)][(lane >> 4) * 8]);
      #pragma unroll
      for (int mi = 0; mi < 2; mi++)
        acc[mi][nj] = __builtin_amdgcn_mfma_f32_16x16x32_bf16(af[mi], bfr, acc[mi][nj], 0, 0, 0);
    }
  }

  #pragma unroll
  for (int h = 0; h < 2; h++){
    __syncthreads();
    if (wm == h){
      #pragma unroll
      for (int mi = 0; mi < 2; mi++)
        #pragma unroll
        for (int nj = 0; nj < 4; nj++)
          #pragma unroll
          for (int q = 0; q < 4; q++)
            epi[mi * 16 + (lane >> 4) * 4 + q][wn * 64 + nj * 16 + (lane & 15)] = acc[mi][nj][q];
    }
    __syncthreads();
    #pragma unroll
    for (int c = 0; c < 4; c++){
      int idx = c * 256 + tid;
      int r = idx >> 5;
      int col = (idx & 31) * 4;
      int row = bm0 + h * 32 + r;
      size_t o = (size_t)row * Dd + bn0 + col;
      f32x4 y = *(const f32x4*)&epi[r][col];
      f32x4 bv = *(const f32x4*)(biasrow + bn0 + col);
      f32x4 x0v;
      if constexpr (X0BF){
        u16x4 xv = *(const u16x4*)(x0b + o);
        #pragma unroll
        for (int j = 0; j < 4; j++) x0v[j] = bf2f(xv[j]);
      } else {
        x0v = *(const f32x4*)(x0f + o);
      }
      f32x4 xo;
      if constexpr (MODE == 0){
        xo = x0v;
      } else {
        u16x4 xv = *(const u16x4*)(xst + o);
        #pragma unroll
        for (int j = 0; j < 4; j++) xo[j] = bf2f(xv[j]);
      }
      f32x4 xn;
      #pragma unroll
      for (int j = 0; j < 4; j++) xn[j] = xo[j] + x0v[j] * (bv[j] + y[j]);
      if constexpr (MODE == 2){
        *(f32x4*)(out + o) = xn;
      } else {
        u16x4 xnb;
        #pragma unroll
        for (int j = 0; j < 4; j++) xnb[j] = f2bf(xn[j]);
        *(u16x4*)(xst + o) = xnb;
      }
      if constexpr (MODE != 2){
        // fused next-layer gate: partial logits over this block's 128 cols
        float s[4];
        #pragma unroll
        for (int e = 0; e < 4; e++){
          u16x4 gv = *(const u16x4*)(gw16 + (size_t)e * Dd + bn0 + col);
          s[e] = xn[0] * bf2f(gv[0]) + xn[1] * bf2f(gv[1])
               + xn[2] * bf2f(gv[2]) + xn[3] * bf2f(gv[3]);
        }
        #pragma unroll
        for (int m = 1; m < 32; m <<= 1)
          #pragma unroll
          for (int e = 0; e < 4; e++) s[e] += __shfl_xor(s[e], m, 64);
        if ((tid & 31) == 0){
          f32x4 pv; pv[0] = s[0]; pv[1] = s[1]; pv[2] = s[2]; pv[3] = s[3];
          *(f32x4*)(plog + ((size_t)blockIdx.y * Bb + row) * 4) = pv;
        }
      }
    }
  }
}

extern "C" void kernel_launch(void* const* d_in, const int* in_sizes, int n_in,
                              void* d_out, int out_size, void* d_ws, size_t ws_size,
                              hipStream_t stream){
  (void)in_sizes; (void)n_in; (void)out_size;
  const float* inp  = (const float*)d_in[0];
  const float* U    = (const float*)d_in[1];
  const float* V    = (const float*)d_in[2];
  const float* C    = (const float*)d_in[3];
  const float* gw   = (const float*)d_in[4];
  const float* bias = (const float*)d_in[5];
  float* out = (float*)d_out;

  char* ws = (char*)d_ws;
  size_t o = 0;
  unsigned short* xb  = (unsigned short*)(ws + o); o += (size_t)Bb * Dd * 2;          // 33.55 MB (bf16 state)
  unsigned short* vxp = (unsigned short*)(ws + o); o += (size_t)4 * Bb * 256 * 2;     // 16.78 MB (bf16 partials)
  unsigned short* wb  = (unsigned short*)(ws + o); o += (size_t)Bb * 256 * 2;         //  4.19 MB
  float*          gsb = (float*)(ws + o);          o += (size_t)Bb * 4 * 4;           //  0.13 MB
  float*          plog= (float*)(ws + o);          o += (size_t)16 * Bb * 4 * 4;      //  2.10 MB
  unsigned short* vft = (unsigned short*)(ws + o); o += (size_t)Ll * 256 * Dd * 2;    //  3.15 MB
  unsigned short* uft = (unsigned short*)(ws + o); o += (size_t)Ll * Dd * 256 * 2;    //  3.15 MB
  unsigned short* cb16= (unsigned short*)(ws + o); o += (size_t)Ll * Ee * Rr * Rr * 2;//  0.10 MB
  unsigned short* g16 = (unsigned short*)(ws + o); o += (size_t)Ee * Dd * 2;          //  0.02 MB
  if (ws_size < o) return;
  unsigned short* x0b = nullptr;
  if (ws_size >= o + (size_t)Bb * Dd * 2){
    x0b = (unsigned short*)(ws + o); o += (size_t)Bb * Dd * 2;                        // 33.55 MB (bf16 x0)
  }
  const bool hx = (x0b != nullptr);

  prep_w_k<<<1024, 256, 0, stream>>>(U, V, C, gw, vft, uft, cb16, g16);
  if (hx) cast_x_k<<<2048, 256, 0, stream>>>(inp, x0b);

  for (int l = 0; l < Ll; l++){
    const unsigned short* vftl = vft + (size_t)l * 256 * Dd;
    const unsigned short* uftl = uft + (size_t)l * Dd * 256;
    const unsigned short* cbl  = cb16 + (size_t)l * Ee * Rr * Rr;
    const float* biasl = bias + (size_t)l * Dd;

    if (l == 0){
      if (hx){
        gate_k<false><<<Bb / 4, 256, 0, stream>>>(x0b, g16, gsb);
        gemm1_k<false><<<dim3(Bb / 64, 2, 4), 256, 0, stream>>>(x0b, vftl, vxp);
      } else {
        gate_k<true><<<Bb / 4, 256, 0, stream>>>(inp, g16, gsb);
        gemm1_k<true><<<dim3(Bb / 64, 2, 4), 256, 0, stream>>>(inp, vftl, vxp);
      }
      gemm2_k<false><<<dim3(Bb / 64, Ee), 256, 0, stream>>>(vxp, cbl, gsb, plog, wb);
    } else {
      gemm1_k<false><<<dim3(Bb / 64, 2, 4), 256, 0, stream>>>(xb, vftl, vxp);
      gemm2_k<true><<<dim3(Bb / 64, Ee), 256, 0, stream>>>(vxp, cbl, gsb, plog, wb);
    }

    dim3 g3(Bb / 64, Dd / 128);
    if (l == 0){
      if (hx) gemm3_k<0, true ><<<g3, 256, 0, stream>>>(wb, uftl, inp, x0b, xb, biasl, out, g16, plog);
      else    gemm3_k<0, false><<<g3, 256, 0, stream>>>(wb, uftl, inp, x0b, xb, biasl, out, g16, plog);
    } else if (l == 1){
      if (hx) gemm3_k<1, true ><<<g3, 256, 0, stream>>>(wb, uftl, inp, x0b, xb, biasl, out, g16, plog);
      else    gemm3_k<1, false><<<g3, 256, 0, stream>>>(wb, uftl, inp, x0b, xb, biasl, out, g16, plog);
    } else {
      if (hx) gemm3_k<2, true ><<<g3, 256, 0, stream>>>(wb, uftl, inp, x0b, xb, biasl, out, g16, plog);
      else    gemm3_k<2, false><<<g3, 256, 0, stream>>>(wb, uftl, inp, x0b, xb, biasl, out, g16, plog);
    }
  }
}

// Round 7
// 213.479 us; speedup vs baseline: 1.8773x; 1.0214x over previous
//
#include <hip/hip_runtime.h>
#include <cmath>

#define Bb 8192
#define Dd 2048
#define Rr 64
#define Ee 4
#define Ll 3

typedef __bf16 bf16x8 __attribute__((ext_vector_type(8)));
typedef float f32x4 __attribute__((ext_vector_type(4)));
typedef unsigned short u16x8 __attribute__((ext_vector_type(8)));
typedef unsigned short u16x4 __attribute__((ext_vector_type(4)));

__device__ __forceinline__ unsigned short f2bf(float f){
  unsigned u = __builtin_bit_cast(unsigned, f);
  u += 0x7fffu + ((u >> 16) & 1u);
  return (unsigned short)(u >> 16);
}
__device__ __forceinline__ float bf2f(unsigned short h){
  return __builtin_bit_cast(float, ((unsigned)h) << 16);
}

// ---------------- cast: x0b = bf16(inp) ----------------
__global__ __launch_bounds__(256) void cast_x_k(const float* __restrict__ x,
                                                unsigned short* __restrict__ xb0){
  const int n4 = Bb * Dd / 4;
  for (int i = blockIdx.x * blockDim.x + threadIdx.x; i < n4; i += gridDim.x * blockDim.x){
    f32x4 v = *((const f32x4*)x + i);
    u16x4 o;
    o[0] = f2bf(v[0]); o[1] = f2bf(v[1]); o[2] = f2bf(v[2]); o[3] = f2bf(v[3]);
    *((u16x4*)xb0 + i) = o;
  }
}

// ---------------- prep: transpose/cast weights ----------------
__global__ __launch_bounds__(256) void prep_w_k(const float* __restrict__ U,
                                                const float* __restrict__ V,
                                                const float* __restrict__ C,
                                                const float* __restrict__ gw,
                                                unsigned short* __restrict__ VfT,
                                                unsigned short* __restrict__ UfT,
                                                unsigned short* __restrict__ cb16,
                                                unsigned short* __restrict__ gw16){
  const int NV = Ll * 256 * Dd;
  const int NU = Ll * Dd * 256;
  const int NC = Ll * Ee * Rr * Rr;
  const int NG = Ee * Dd;
  const int total = NV + NU + NC + NG;
  for (int idx = blockIdx.x * blockDim.x + threadIdx.x; idx < total; idx += gridDim.x * blockDim.x){
    if (idx < NV){
      int l = idx / (256 * Dd); int rem = idx - l * 256 * Dd;
      int n = rem / Dd, d = rem - n * Dd;
      int e = n >> 6, r = n & 63;
      VfT[idx] = f2bf(V[(((size_t)l * Ee + e) * Dd + d) * Rr + r]);
    } else if (idx < NV + NU){
      int j = idx - NV;
      int l = j / (Dd * 256); int rem = j - l * Dd * 256;
      int d = rem / 256, k = rem - d * 256;
      int e = k >> 6, s = k & 63;
      UfT[j] = f2bf(U[(((size_t)l * Ee + e) * Dd + d) * Rr + s]);
    } else if (idx < NV + NU + NC){
      int j = idx - NV - NU;
      cb16[j] = f2bf(C[j]);
    } else {
      int j = idx - NV - NU - NC;
      gw16[j] = f2bf(gw[j]);
    }
  }
}

// ---------------- gate (layer 0 only): one wave per row, coalesced ----------------
template<bool AF32>
__global__ __launch_bounds__(256) void gate_k(const void* __restrict__ xv,
                                              const unsigned short* __restrict__ gw16,
                                              float* __restrict__ gs){
  const int lane = threadIdx.x & 63;
  const int w = threadIdx.x >> 6;
  const int row = blockIdx.x * 4 + w;
  float s0 = 0.f, s1 = 0.f, s2 = 0.f, s3 = 0.f;
  #pragma unroll
  for (int c = 0; c < 4; c++){
    const int k = c * 512 + lane * 8;
    float xf[8];
    if constexpr (AF32){
      const float* xr = (const float*)xv + (size_t)row * Dd + k;
      f32x4 v0 = *(const f32x4*)xr;
      f32x4 v1 = *(const f32x4*)(xr + 4);
      #pragma unroll
      for (int u = 0; u < 4; u++){ xf[u] = v0[u]; xf[4 + u] = v1[u]; }
    } else {
      u16x8 xvv = *(const u16x8*)((const unsigned short*)xv + (size_t)row * Dd + k);
      #pragma unroll
      for (int u = 0; u < 8; u++) xf[u] = bf2f(xvv[u]);
    }
    u16x8 g0v = *(const u16x8*)(gw16 + 0 * Dd + k);
    u16x8 g1v = *(const u16x8*)(gw16 + 1 * Dd + k);
    u16x8 g2v = *(const u16x8*)(gw16 + 2 * Dd + k);
    u16x8 g3v = *(const u16x8*)(gw16 + 3 * Dd + k);
    #pragma unroll
    for (int u = 0; u < 8; u++){
      s0 += xf[u] * bf2f(g0v[u]);
      s1 += xf[u] * bf2f(g1v[u]);
      s2 += xf[u] * bf2f(g2v[u]);
      s3 += xf[u] * bf2f(g3v[u]);
    }
  }
  #pragma unroll
  for (int m = 1; m < 64; m <<= 1){
    s0 += __shfl_xor(s0, m, 64);
    s1 += __shfl_xor(s1, m, 64);
    s2 += __shfl_xor(s2, m, 64);
    s3 += __shfl_xor(s3, m, 64);
  }
  if (lane == 0){
    float mx = fmaxf(fmaxf(s0, s1), fmaxf(s2, s3));
    float e0 = __expf(s0 - mx), e1 = __expf(s1 - mx), e2 = __expf(s2 - mx), e3 = __expf(s3 - mx);
    float inv = 1.f / (e0 + e1 + e2 + e3);
    f32x4 g; g[0] = e0 * inv; g[1] = e1 * inv; g[2] = e2 * inv; g[3] = e3 * inv;
    *(f32x4*)(gs + (size_t)row * 4) = g;
  }
}

// ============ G1: T = X @ VfT, split-K=4, bf16 partials, BK=64 ============
template<bool AF32>
__global__ __launch_bounds__(256) void gemm1_k(const void* __restrict__ Av,
                                               const unsigned short* __restrict__ BT,
                                               unsigned short* __restrict__ vxp){
  const int bm0 = blockIdx.x * 64;
  const int bn0 = blockIdx.y * 128;
  const int z   = blockIdx.z;
  const int kc0 = z * 512;
  const int tid = threadIdx.x;
  const int lane = tid & 63;
  const int wv = tid >> 6;
  const int wm = wv >> 1, wn = wv & 1;

  __shared__ __align__(16) char smraw[27648];
  unsigned short (*As)[72] = (unsigned short (*)[72])smraw;            // 9216 B
  unsigned short (*Bs)[72] = (unsigned short (*)[72])(smraw + 9216);   // 18432 B
  float (*epi)[132] = (float (*)[132])smraw;                           // 16896 B (half-tile)

  f32x4 acc[2][4] = {};
  const int arow = tid >> 2;
  const int aseg = tid & 3;

  const float* Af = (const float*)Av;
  const unsigned short* Ab = (const unsigned short*)Av;

  f32x4 a4[4]; u16x8 ar[2]; u16x8 br[4];
  if constexpr (AF32){
    #pragma unroll
    for (int j = 0; j < 4; j++)
      a4[j] = *(const f32x4*)(Af + (size_t)(bm0 + arow) * Dd + kc0 + aseg * 16 + j * 4);
  } else {
    ar[0] = *(const u16x8*)(Ab + (size_t)(bm0 + arow) * Dd + kc0 + aseg * 16);
    ar[1] = *(const u16x8*)(Ab + (size_t)(bm0 + arow) * Dd + kc0 + aseg * 16 + 8);
  }
  br[0] = *(const u16x8*)(BT + (size_t)(bn0 + arow) * Dd + kc0 + aseg * 16);
  br[1] = *(const u16x8*)(BT + (size_t)(bn0 + arow) * Dd + kc0 + aseg * 16 + 8);
  br[2] = *(const u16x8*)(BT + (size_t)(bn0 + arow + 64) * Dd + kc0 + aseg * 16);
  br[3] = *(const u16x8*)(BT + (size_t)(bn0 + arow + 64) * Dd + kc0 + aseg * 16 + 8);

  for (int k0 = kc0; k0 < kc0 + 512; k0 += 64){
    __syncthreads();
    if constexpr (AF32){
      u16x8 av0, av1;
      #pragma unroll
      for (int j = 0; j < 4; j++){
        av0[j] = f2bf(a4[0][j]); av0[4 + j] = f2bf(a4[1][j]);
        av1[j] = f2bf(a4[2][j]); av1[4 + j] = f2bf(a4[3][j]);
      }
      *(u16x8*)(&As[arow][aseg * 16])     = av0;
      *(u16x8*)(&As[arow][aseg * 16 + 8]) = av1;
    } else {
      *(u16x8*)(&As[arow][aseg * 16])     = ar[0];
      *(u16x8*)(&As[arow][aseg * 16 + 8]) = ar[1];
    }
    *(u16x8*)(&Bs[arow][aseg * 16])          = br[0];
    *(u16x8*)(&Bs[arow][aseg * 16 + 8])      = br[1];
    *(u16x8*)(&Bs[arow + 64][aseg * 16])     = br[2];
    *(u16x8*)(&Bs[arow + 64][aseg * 16 + 8]) = br[3];
    __syncthreads();

    int kn = k0 + 64;
    if (kn < kc0 + 512){
      if constexpr (AF32){
        #pragma unroll
        for (int j = 0; j < 4; j++)
          a4[j] = *(const f32x4*)(Af + (size_t)(bm0 + arow) * Dd + kn + aseg * 16 + j * 4);
      } else {
        ar[0] = *(const u16x8*)(Ab + (size_t)(bm0 + arow) * Dd + kn + aseg * 16);
        ar[1] = *(const u16x8*)(Ab + (size_t)(bm0 + arow) * Dd + kn + aseg * 16 + 8);
      }
      br[0] = *(const u16x8*)(BT + (size_t)(bn0 + arow) * Dd + kn + aseg * 16);
      br[1] = *(const u16x8*)(BT + (size_t)(bn0 + arow) * Dd + kn + aseg * 16 + 8);
      br[2] = *(const u16x8*)(BT + (size_t)(bn0 + arow + 64) * Dd + kn + aseg * 16);
      br[3] = *(const u16x8*)(BT + (size_t)(bn0 + arow + 64) * Dd + kn + aseg * 16 + 8);
    }

    #pragma unroll
    for (int ks = 0; ks < 2; ks++){
      bf16x8 af[2];
      #pragma unroll
      for (int mi = 0; mi < 2; mi++)
        af[mi] = *reinterpret_cast<const bf16x8*>(&As[wm * 32 + mi * 16 + (lane & 15)][ks * 32 + (lane >> 4) * 8]);
      #pragma unroll
      for (int nj = 0; nj < 4; nj++){
        bf16x8 bfr = *reinterpret_cast<const bf16x8*>(&Bs[wn * 64 + nj * 16 + (lane & 15)][ks * 32 + (lane >> 4) * 8]);
        #pragma unroll
        for (int mi = 0; mi < 2; mi++)
          acc[mi][nj] = __builtin_amdgcn_mfma_f32_16x16x32_bf16(af[mi], bfr, acc[mi][nj], 0, 0, 0);
      }
    }
  }

  unsigned short* outz = vxp + (size_t)z * Bb * 256;
  #pragma unroll
  for (int h = 0; h < 2; h++){
    __syncthreads();
    if (wm == h){
      #pragma unroll
      for (int mi = 0; mi < 2; mi++)
        #pragma unroll
        for (int nj = 0; nj < 4; nj++)
          #pragma unroll
          for (int q = 0; q < 4; q++)
            epi[mi * 16 + (lane >> 4) * 4 + q][wn * 64 + nj * 16 + (lane & 15)] = acc[mi][nj][q];
    }
    __syncthreads();
    #pragma unroll
    for (int c = 0; c < 4; c++){
      int idx = c * 256 + tid;
      int r = idx >> 5;
      int col = (idx & 31) * 4;
      f32x4 v = *(const f32x4*)&epi[r][col];
      u16x4 ov;
      #pragma unroll
      for (int j = 0; j < 4; j++) ov[j] = f2bf(v[j]);
      *(u16x4*)(outz + (size_t)(bm0 + h * 32 + r) * 256 + bn0 + col) = ov;
    }
  }
}

// ============ G2: block-diag C; sums bf16 partials; softmax from plog (l>=1) ============
template<bool FROMPLOG>
__global__ __launch_bounds__(256) void gemm2_k(const unsigned short* __restrict__ vxp,
                                               const unsigned short* __restrict__ cb,
                                               const float* __restrict__ gsb,
                                               const float* __restrict__ plog,
                                               unsigned short* __restrict__ wb){
  const int bm0 = blockIdx.x * 64;
  const int e   = blockIdx.y;
  const int tid = threadIdx.x;
  const int lane = tid & 63;
  const int wv = tid >> 6;
  const int wm = wv >> 1, wn = wv & 1;

  __shared__ __align__(16) char smraw[19456];
  unsigned short (*As)[72] = (unsigned short (*)[72])smraw;            // 9216
  unsigned short (*Bs)[72] = (unsigned short (*)[72])(smraw + 9216);   // 9216
  float (*gs_l)[4] = (float (*)[4])(smraw + 18432);                    // 1024
  unsigned short (*epi)[72] = (unsigned short (*)[72])smraw;           // union As

  if constexpr (FROMPLOG){
    int r = tid >> 2, q = tid & 3;
    f32x4 s = {0.f, 0.f, 0.f, 0.f};
    #pragma unroll
    for (int ci = 0; ci < 4; ci++)
      s += *(const f32x4*)(plog + ((size_t)(q * 4 + ci) * Bb + bm0 + r) * 4);
    #pragma unroll
    for (int j = 0; j < 4; j++){
      s[j] += __shfl_xor(s[j], 1, 64);
      s[j] += __shfl_xor(s[j], 2, 64);
    }
    if (q == 0){
      float mx = fmaxf(fmaxf(s[0], s[1]), fmaxf(s[2], s[3]));
      float e0 = __expf(s[0] - mx), e1 = __expf(s[1] - mx), e2 = __expf(s[2] - mx), e3 = __expf(s[3] - mx);
      float inv = 1.f / (e0 + e1 + e2 + e3);
      f32x4 g; g[0] = e0 * inv; g[1] = e1 * inv; g[2] = e2 * inv; g[3] = e3 * inv;
      *(f32x4*)&gs_l[r][0] = g;
    }
  } else {
    if (tid < 64) *(f32x4*)&gs_l[tid][0] = *(const f32x4*)(gsb + (size_t)(bm0 + tid) * 4);
  }

  const int arow = tid >> 2;
  const int aseg = tid & 3;

  float tv[16];
  #pragma unroll
  for (int j = 0; j < 16; j++) tv[j] = 0.f;
  #pragma unroll
  for (int z = 0; z < 4; z++){
    const unsigned short* vz = vxp + ((size_t)z * Bb + bm0 + arow) * 256 + e * 64 + aseg * 16;
    u16x8 p0 = *(const u16x8*)vz;
    u16x8 p1 = *(const u16x8*)(vz + 8);
    #pragma unroll
    for (int j = 0; j < 8; j++){ tv[j] += bf2f(p0[j]); tv[8 + j] += bf2f(p1[j]); }
  }
  u16x8 av0, av1;
  #pragma unroll
  for (int j = 0; j < 4; j++){
    av0[j] = f2bf(tanhf(tv[j]));     av0[4 + j] = f2bf(tanhf(tv[4 + j]));
    av1[j] = f2bf(tanhf(tv[8 + j])); av1[4 + j] = f2bf(tanhf(tv[12 + j]));
  }
  *(u16x8*)(&As[arow][aseg * 16]) = av0;
  *(u16x8*)(&As[arow][aseg * 16 + 8]) = av1;
  *(u16x8*)(&Bs[arow][aseg * 16])     = *(const u16x8*)(cb + e * 4096 + arow * 64 + aseg * 16);
  *(u16x8*)(&Bs[arow][aseg * 16 + 8]) = *(const u16x8*)(cb + e * 4096 + arow * 64 + aseg * 16 + 8);
  __syncthreads();

  f32x4 acc[2][2] = {};
  #pragma unroll
  for (int kk = 0; kk < 2; kk++){
    bf16x8 af[2];
    #pragma unroll
    for (int mi = 0; mi < 2; mi++)
      af[mi] = *reinterpret_cast<const bf16x8*>(&As[wm * 32 + mi * 16 + (lane & 15)][kk * 32 + (lane >> 4) * 8]);
    #pragma unroll
    for (int nj = 0; nj < 2; nj++){
      bf16x8 bfr = *reinterpret_cast<const bf16x8*>(&Bs[wn * 32 + nj * 16 + (lane & 15)][kk * 32 + (lane >> 4) * 8]);
      #pragma unroll
      for (int mi = 0; mi < 2; mi++)
        acc[mi][nj] = __builtin_amdgcn_mfma_f32_16x16x32_bf16(af[mi], bfr, acc[mi][nj], 0, 0, 0);
    }
  }

  __syncthreads();
  #pragma unroll
  for (int mi = 0; mi < 2; mi++)
    #pragma unroll
    for (int nj = 0; nj < 2; nj++)
      #pragma unroll
      for (int q = 0; q < 4; q++){
        int row = wm * 32 + mi * 16 + (lane >> 4) * 4 + q;
        int col = wn * 32 + nj * 16 + (lane & 15);
        float g = gs_l[row][e];
        epi[row][col] = f2bf(g * tanhf(acc[mi][nj][q]));
      }
  __syncthreads();
  #pragma unroll
  for (int c = 0; c < 2; c++){
    int idx = c * 256 + tid;
    int row = idx >> 3;
    int col = (idx & 7) * 8;
    *(u16x8*)(wb + (size_t)(bm0 + row) * 256 + e * 64 + col) = *(const u16x8*)(&epi[row][col]);
  }
}

// ============ G3: Y = wb @ UfT; x_new = xold + x0*(bias + Y); fused next-gate ============
// 128x128 tile, 4 waves each 64x64 (16 MFMA/K-step), BK=32, reg-prefetch.
// MODE 0: xold = x0, write bf16 state + plog       (layer 0)
// MODE 1: xold = bf16 state RMW, + plog            (layer 1)
// MODE 2: xold = bf16 state, write fp32 out        (layer 2, no plog)
// X0BF: x0 read as bf16 (x0b) vs fp32 (inp)
template<int MODE, bool X0BF>
__global__ __launch_bounds__(256, 4) void gemm3_k(const unsigned short* __restrict__ A,
                                                  const unsigned short* __restrict__ BT,
                                                  const float* __restrict__ x0f,
                                                  const unsigned short* __restrict__ x0b,
                                                  unsigned short* __restrict__ xst,
                                                  const float* __restrict__ biasrow,
                                                  float* __restrict__ out,
                                                  const unsigned short* __restrict__ gw16,
                                                  float* __restrict__ plog){
  const int bm0 = blockIdx.x * 128;
  const int bn0 = blockIdx.y * 128;
  const int tid = threadIdx.x;
  const int lane = tid & 63;
  const int wv = tid >> 6;
  const int wm = wv >> 1, wn = wv & 1;   // wave tile: rows wm*64.., cols wn*64..

  __shared__ __align__(16) char smraw[20480];
  unsigned short (*As)[40] = (unsigned short (*)[40])smraw;            // 128x40x2 = 10240 B
  unsigned short (*Bs)[40] = (unsigned short (*)[40])(smraw + 10240);  // 10240 B
  float (*epi)[132] = (float (*)[132])smraw;                           // 32x132x4 = 16896 B

  f32x4 acc[4][4] = {};
  const int arow = tid >> 2;   // 0..63 (handles rows arow and arow+64)
  const int aseg = tid & 3;

  u16x8 ar0 = *(const u16x8*)(A + (size_t)(bm0 + arow) * 256 + aseg * 8);
  u16x8 ar1 = *(const u16x8*)(A + (size_t)(bm0 + arow + 64) * 256 + aseg * 8);
  u16x8 br0 = *(const u16x8*)(BT + (size_t)(bn0 + arow) * 256 + aseg * 8);
  u16x8 br1 = *(const u16x8*)(BT + (size_t)(bn0 + arow + 64) * 256 + aseg * 8);

  for (int k0 = 0; k0 < 256; k0 += 32){
    __syncthreads();
    *(u16x8*)(&As[arow][aseg * 8])      = ar0;
    *(u16x8*)(&As[arow + 64][aseg * 8]) = ar1;
    *(u16x8*)(&Bs[arow][aseg * 8])      = br0;
    *(u16x8*)(&Bs[arow + 64][aseg * 8]) = br1;
    __syncthreads();
    if (k0 + 32 < 256){
      ar0 = *(const u16x8*)(A + (size_t)(bm0 + arow) * 256 + k0 + 32 + aseg * 8);
      ar1 = *(const u16x8*)(A + (size_t)(bm0 + arow + 64) * 256 + k0 + 32 + aseg * 8);
      br0 = *(const u16x8*)(BT + (size_t)(bn0 + arow) * 256 + k0 + 32 + aseg * 8);
      br1 = *(const u16x8*)(BT + (size_t)(bn0 + arow + 64) * 256 + k0 + 32 + aseg * 8);
    }
    bf16x8 af[4];
    #pragma unroll
    for (int mi = 0; mi < 4; mi++)
      af[mi] = *reinterpret_cast<const bf16x8*>(&As[wm * 64 + mi * 16 + (lane & 15)][(lane >> 4) * 8]);
    #pragma unroll
    for (int nj = 0; nj < 4; nj++){
      bf16x8 bfr = *reinterpret_cast<const bf16x8*>(&Bs[wn * 64 + nj * 16 + (lane & 15)][(lane >> 4) * 8]);
      #pragma unroll
      for (int mi = 0; mi < 4; mi++)
        acc[mi][nj] = __builtin_amdgcn_mfma_f32_16x16x32_bf16(af[mi], bfr, acc[mi][nj], 0, 0, 0);
    }
  }

  // epilogue: 4 quarter-phases of 32 rows each through LDS
  #pragma unroll
  for (int h = 0; h < 4; h++){
    __syncthreads();
    if (wm == (h >> 1)){
      const int mib = (h & 1) * 2;
      #pragma unroll
      for (int m2 = 0; m2 < 2; m2++)
        #pragma unroll
        for (int nj = 0; nj < 4; nj++)
          #pragma unroll
          for (int q = 0; q < 4; q++)
            epi[m2 * 16 + (lane >> 4) * 4 + q][wn * 64 + nj * 16 + (lane & 15)] = acc[mib + m2][nj][q];
    }
    __syncthreads();
    #pragma unroll
    for (int c = 0; c < 4; c++){
      int idx = c * 256 + tid;
      int r = idx >> 5;
      int col = (idx & 31) * 4;
      int row = bm0 + h * 32 + r;
      size_t o = (size_t)row * Dd + bn0 + col;
      f32x4 y = *(const f32x4*)&epi[r][col];
      f32x4 bv = *(const f32x4*)(biasrow + bn0 + col);
      f32x4 x0v;
      if constexpr (X0BF){
        u16x4 xv = *(const u16x4*)(x0b + o);
        #pragma unroll
        for (int j = 0; j < 4; j++) x0v[j] = bf2f(xv[j]);
      } else {
        x0v = *(const f32x4*)(x0f + o);
      }
      f32x4 xo;
      if constexpr (MODE == 0){
        xo = x0v;
      } else {
        u16x4 xv = *(const u16x4*)(xst + o);
        #pragma unroll
        for (int j = 0; j < 4; j++) xo[j] = bf2f(xv[j]);
      }
      f32x4 xn;
      #pragma unroll
      for (int j = 0; j < 4; j++) xn[j] = xo[j] + x0v[j] * (bv[j] + y[j]);
      if constexpr (MODE == 2){
        *(f32x4*)(out + o) = xn;
      } else {
        u16x4 xnb;
        #pragma unroll
        for (int j = 0; j < 4; j++) xnb[j] = f2bf(xn[j]);
        *(u16x4*)(xst + o) = xnb;
      }
      if constexpr (MODE != 2){
        float s[4];
        #pragma unroll
        for (int e = 0; e < 4; e++){
          u16x4 gv = *(const u16x4*)(gw16 + (size_t)e * Dd + bn0 + col);
          s[e] = xn[0] * bf2f(gv[0]) + xn[1] * bf2f(gv[1])
               + xn[2] * bf2f(gv[2]) + xn[3] * bf2f(gv[3]);
        }
        #pragma unroll
        for (int m = 1; m < 32; m <<= 1)
          #pragma unroll
          for (int e = 0; e < 4; e++) s[e] += __shfl_xor(s[e], m, 64);
        if ((tid & 31) == 0){
          f32x4 pv; pv[0] = s[0]; pv[1] = s[1]; pv[2] = s[2]; pv[3] = s[3];
          *(f32x4*)(plog + ((size_t)blockIdx.y * Bb + row) * 4) = pv;
        }
      }
    }
  }
}

extern "C" void kernel_launch(void* const* d_in, const int* in_sizes, int n_in,
                              void* d_out, int out_size, void* d_ws, size_t ws_size,
                              hipStream_t stream){
  (void)in_sizes; (void)n_in; (void)out_size;
  const float* inp  = (const float*)d_in[0];
  const float* U    = (const float*)d_in[1];
  const float* V    = (const float*)d_in[2];
  const float* C    = (const float*)d_in[3];
  const float* gw   = (const float*)d_in[4];
  const float* bias = (const float*)d_in[5];
  float* out = (float*)d_out;

  char* ws = (char*)d_ws;
  size_t o = 0;
  unsigned short* xb  = (unsigned short*)(ws + o); o += (size_t)Bb * Dd * 2;          // 33.55 MB (bf16 state)
  unsigned short* vxp = (unsigned short*)(ws + o); o += (size_t)4 * Bb * 256 * 2;     // 16.78 MB (bf16 partials)
  unsigned short* wb  = (unsigned short*)(ws + o); o += (size_t)Bb * 256 * 2;         //  4.19 MB
  float*          gsb = (float*)(ws + o);          o += (size_t)Bb * 4 * 4;           //  0.13 MB
  float*          plog= (float*)(ws + o);          o += (size_t)16 * Bb * 4 * 4;      //  2.10 MB
  unsigned short* vft = (unsigned short*)(ws + o); o += (size_t)Ll * 256 * Dd * 2;    //  3.15 MB
  unsigned short* uft = (unsigned short*)(ws + o); o += (size_t)Ll * Dd * 256 * 2;    //  3.15 MB
  unsigned short* cb16= (unsigned short*)(ws + o); o += (size_t)Ll * Ee * Rr * Rr * 2;//  0.10 MB
  unsigned short* g16 = (unsigned short*)(ws + o); o += (size_t)Ee * Dd * 2;          //  0.02 MB
  if (ws_size < o) return;
  unsigned short* x0b = nullptr;
  if (ws_size >= o + (size_t)Bb * Dd * 2){
    x0b = (unsigned short*)(ws + o); o += (size_t)Bb * Dd * 2;                        // 33.55 MB (bf16 x0)
  }
  const bool hx = (x0b != nullptr);

  prep_w_k<<<1024, 256, 0, stream>>>(U, V, C, gw, vft, uft, cb16, g16);
  if (hx) cast_x_k<<<2048, 256, 0, stream>>>(inp, x0b);

  for (int l = 0; l < Ll; l++){
    const unsigned short* vftl = vft + (size_t)l * 256 * Dd;
    const unsigned short* uftl = uft + (size_t)l * Dd * 256;
    const unsigned short* cbl  = cb16 + (size_t)l * Ee * Rr * Rr;
    const float* biasl = bias + (size_t)l * Dd;

    if (l == 0){
      if (hx){
        gate_k<false><<<Bb / 4, 256, 0, stream>>>(x0b, g16, gsb);
        gemm1_k<false><<<dim3(Bb / 64, 2, 4), 256, 0, stream>>>(x0b, vftl, vxp);
      } else {
        gate_k<true><<<Bb / 4, 256, 0, stream>>>(inp, g16, gsb);
        gemm1_k<true><<<dim3(Bb / 64, 2, 4), 256, 0, stream>>>(inp, vftl, vxp);
      }
      gemm2_k<false><<<dim3(Bb / 64, Ee), 256, 0, stream>>>(vxp, cbl, gsb, plog, wb);
    } else {
      gemm1_k<false><<<dim3(Bb / 64, 2, 4), 256, 0, stream>>>(xb, vftl, vxp);
      gemm2_k<true><<<dim3(Bb / 64, Ee), 256, 0, stream>>>(vxp, cbl, gsb, plog, wb);
    }

    dim3 g3(Bb / 128, Dd / 128);
    if (l == 0){
      if (hx) gemm3_k<0, true ><<<g3, 256, 0, stream>>>(wb, uftl, inp, x0b, xb, biasl, out, g16, plog);
      else    gemm3_k<0, false><<<g3, 256, 0, stream>>>(wb, uftl, inp, x0b, xb, biasl, out, g16, plog);
    } else if (l == 1){
      if (hx) gemm3_k<1, true ><<<g3, 256, 0, stream>>>(wb, uftl, inp, x0b, xb, biasl, out, g16, plog);
      else    gemm3_k<1, false><<<g3, 256, 0, stream>>>(wb, uftl, inp, x0b, xb, biasl, out, g16, plog);
    } else {
      if (hx) gemm3_k<2, true ><<<g3, 256, 0, stream>>>(wb, uftl, inp, x0b, xb, biasl, out, g16, plog);
      else    gemm3_k<2, false><<<g3, 256, 0, stream>>>(wb, uftl, inp, x0b, xb, biasl, out, g16, plog);
    }
  }
}